// Round 1
// baseline (1481.669 us; speedup 1.0000x reference)
//
#include <hip/hip_runtime.h>

#define Bb 8
#define Nn 8192
#define Hh 256
#define NUP 2048
#define MM 5
#define RPB 16

// Order-preserving float->uint encoding for atomicMax-based float max.
__device__ __forceinline__ unsigned flipf(float f) {
    unsigned u = __float_as_uint(f);
    return (u & 0x80000000u) ? ~u : (u | 0x80000000u);
}
__device__ __forceinline__ float unflip(unsigned u) {
    unsigned bits = (u & 0x80000000u) ? (u & 0x7FFFFFFFu) : ~u;
    return __uint_as_float(bits);
}

// Kernel A: stable descending rank of scores per batch; up_mask = rank < NUP.
// rank(i) = #{j: s[j] > s[i]} + #{j < i: s[j] == s[i]}  (matches stable argsort(-s))
__global__ void rank_kernel(const float* __restrict__ scores, int* __restrict__ mask) {
    int b = blockIdx.y;
    int i = blockIdx.x * 256 + threadIdx.x;
    const float* s = scores + b * Nn;
    float si = s[i];
    __shared__ float tile[256];
    int cnt = 0;
    for (int t = 0; t < Nn; t += 256) {
        __syncthreads();
        tile[threadIdx.x] = s[t + threadIdx.x];
        __syncthreads();
        #pragma unroll 8
        for (int jj = 0; jj < 256; jj++) {
            float sj = tile[jj];
            int j = t + jj;
            cnt += (sj > si || (sj == si && j < i)) ? 1 : 0;
        }
    }
    mask[b * Nn + i] = (cnt < NUP) ? 1 : 0;
}

// Kernel B: feat = concat(h, s_l, scores) @ W + b for all rows.
// Down rows -> float feature; up rows -> flipped(-inf) sentinel (0x007FFFFF).
// Written into d_out's first B*N*H words.
__global__ void feat_kernel(const float* __restrict__ h, const float* __restrict__ sl,
                            const float* __restrict__ sc, const float* __restrict__ W,
                            const float* __restrict__ bias, const int* __restrict__ mask,
                            unsigned* __restrict__ out) {
    int b = blockIdx.y;
    int r0 = blockIdx.x * RPB;
    int tid = threadIdx.x;
    __shared__ float sh[RPB][260];
    const float* hb = h + ((size_t)b * Nn + r0) * Hh;
    #pragma unroll
    for (int r = 0; r < RPB; r++) sh[r][tid] = hb[(size_t)r * Hh + tid];
    if (tid < RPB * 4) {
        int r = tid >> 2, q = tid & 3;
        int node = r0 + r;
        if (q < 3) sh[r][256 + q] = sl[((size_t)b * Nn + node) * 3 + q];
        else       sh[r][259]     = sc[(size_t)b * Nn + node];
    }
    __syncthreads();
    float acc[RPB];
    float bb = bias[tid];
    #pragma unroll
    for (int r = 0; r < RPB; r++) acc[r] = bb;
    for (int k = 0; k < 260; k += 4) {
        float w0 = W[(k + 0) * Hh + tid];
        float w1 = W[(k + 1) * Hh + tid];
        float w2 = W[(k + 2) * Hh + tid];
        float w3 = W[(k + 3) * Hh + tid];
        #pragma unroll
        for (int r = 0; r < RPB; r++) {
            float4 iv = *(const float4*)&sh[r][k];   // 260*4B row = 16B-aligned
            acc[r] += iv.x * w0 + iv.y * w1 + iv.z * w2 + iv.w * w3;
        }
    }
    #pragma unroll
    for (int r = 0; r < RPB; r++) {
        int g = b * Nn + r0 + r;
        out[(size_t)g * Hh + tid] = mask[g] ? 0x007FFFFFu : __float_as_uint(acc[r]);
    }
}

// Kernel C: for each down node, 5 nearest up nodes (global indices) by squared
// 3-D distance; strict '<' everywhere matches top_k's lower-index-first ties.
__global__ void knn_kernel(const float* __restrict__ sl, const int* __restrict__ mask,
                           int* __restrict__ knn) {
    int b = blockIdx.y;
    int i = blockIdx.x * 256 + threadIdx.x;
    int g = b * Nn + i;
    bool down = (mask[g] == 0);
    float xi = sl[(size_t)g * 3 + 0];
    float yi = sl[(size_t)g * 3 + 1];
    float zi = sl[(size_t)g * 3 + 2];
    __shared__ float sx[256], sy[256], sz[256];
    __shared__ int smk[256];
    float bd[MM];
    int bj[MM];
    #pragma unroll
    for (int m = 0; m < MM; m++) { bd[m] = 3.4e38f; bj[m] = -1; }
    for (int t = 0; t < Nn; t += 256) {
        __syncthreads();
        int gj = b * Nn + t + threadIdx.x;
        sx[threadIdx.x] = sl[(size_t)gj * 3 + 0];
        sy[threadIdx.x] = sl[(size_t)gj * 3 + 1];
        sz[threadIdx.x] = sl[(size_t)gj * 3 + 2];
        smk[threadIdx.x] = mask[gj];
        __syncthreads();
        if (down) {
            for (int jj = 0; jj < 256; jj++) {
                float dx = sx[jj] - xi, dy = sy[jj] - yi, dz = sz[jj] - zi;
                float d2 = dx * dx + dy * dy + dz * dz;
                if (smk[jj] && d2 < bd[MM - 1]) {
                    float cd = d2; int cj = t + jj;
                    #pragma unroll
                    for (int p = 0; p < MM; p++) {
                        if (cd < bd[p]) {
                            float td = bd[p]; int tj = bj[p];
                            bd[p] = cd; bj[p] = cj;
                            cd = td; cj = tj;
                        }
                    }
                }
            }
        }
    }
    if (down) {
        #pragma unroll
        for (int m = 0; m < MM; m++) knn[g * MM + m] = bj[m];
    }
}

// Kernel D: scatter-max. One block (64 threads) per down node; each lane owns
// 4 columns; 5 atomicMax per owned column into the up rows of d_out.
__global__ void scatter_kernel(const int* __restrict__ mask, const int* __restrict__ knn,
                               unsigned* __restrict__ out) {
    int b = blockIdx.y;
    int node = blockIdx.x;
    int g = b * Nn + node;
    if (mask[g]) return;
    int lane = threadIdx.x;
    unsigned e[4];
    #pragma unroll
    for (int q = 0; q < 4; q++) {
        float f = __uint_as_float(out[(size_t)g * Hh + lane + 64 * q]);
        e[q] = flipf(f);
    }
    int nb[MM];
    #pragma unroll
    for (int m = 0; m < MM; m++) nb[m] = knn[g * MM + m];
    #pragma unroll
    for (int m = 0; m < MM; m++) {
        size_t base = ((size_t)(b * Nn + nb[m])) * Hh;
        #pragma unroll
        for (int q = 0; q < 4; q++) atomicMax(&out[base + lane + 64 * q], e[q]);
    }
}

// Kernel E: decode up rows (sentinel -> 0), zero down rows, write mask tail.
__global__ void finalize_kernel(const int* __restrict__ mask, unsigned* __restrict__ out) {
    int b = blockIdx.y;
    int node = blockIdx.x;
    int g = b * Nn + node;
    int c = threadIdx.x;
    bool up = mask[g] != 0;
    float v = 0.f;
    if (up) {
        unsigned u = out[(size_t)g * Hh + c];
        v = (u == 0x007FFFFFu) ? 0.f : unflip(u);
    }
    ((float*)out)[(size_t)g * Hh + c] = v;
    if (c == 0) ((float*)out)[(size_t)Bb * Nn * Hh + g] = up ? 1.0f : 0.0f;
}

extern "C" void kernel_launch(void* const* d_in, const int* in_sizes, int n_in,
                              void* d_out, int out_size, void* d_ws, size_t ws_size,
                              hipStream_t stream) {
    const float* h    = (const float*)d_in[0];
    const float* sl   = (const float*)d_in[1];
    const float* sc   = (const float*)d_in[2];
    const float* W    = (const float*)d_in[3];
    const float* bias = (const float*)d_in[4];

    int* mask = (int*)d_ws;                                        // B*N ints
    int* knn  = (int*)((char*)d_ws + (size_t)Bb * Nn * sizeof(int)); // B*N*5 ints
    unsigned* outu = (unsigned*)d_out;

    dim3 blk(256);
    rank_kernel<<<dim3(Nn / 256, Bb), blk, 0, stream>>>(sc, mask);
    feat_kernel<<<dim3(Nn / RPB, Bb), blk, 0, stream>>>(h, sl, sc, W, bias, mask, outu);
    knn_kernel<<<dim3(Nn / 256, Bb), blk, 0, stream>>>(sl, mask, knn);
    scatter_kernel<<<dim3(Nn, Bb), dim3(64), 0, stream>>>(mask, knn, outu);
    finalize_kernel<<<dim3(Nn, Bb), blk, 0, stream>>>(mask, outu);
}

// Round 2
// 967.552 us; speedup vs baseline: 1.5314x; 1.5314x over previous
//
#include <hip/hip_runtime.h>

#define Bb 8
#define Nn 8192
#define Hh 256
#define NUP 2048
#define MM 5
#define RPB 16

// Order-preserving float->uint encoding for atomicMax-based float max.
__device__ __forceinline__ unsigned flipf(float f) {
    unsigned u = __float_as_uint(f);
    return (u & 0x80000000u) ? ~u : (u | 0x80000000u);
}
__device__ __forceinline__ float unflip(unsigned u) {
    unsigned bits = (u & 0x80000000u) ? (u & 0x7FFFFFFFu) : ~u;
    return __uint_as_float(bits);
}

// Kernel A: stable descending rank of scores per batch; up_mask = rank < NUP.
__global__ void rank_kernel(const float* __restrict__ scores, int* __restrict__ mask) {
    int b = blockIdx.y;
    int i = blockIdx.x * 256 + threadIdx.x;
    const float* s = scores + b * Nn;
    float si = s[i];
    __shared__ float tile[256];
    int cnt = 0;
    for (int t = 0; t < Nn; t += 256) {
        __syncthreads();
        tile[threadIdx.x] = s[t + threadIdx.x];
        __syncthreads();
        #pragma unroll 8
        for (int jj = 0; jj < 256; jj++) {
            float sj = tile[jj];
            int j = t + jj;
            cnt += (sj > si || (sj == si && j < i)) ? 1 : 0;
        }
    }
    mask[b * Nn + i] = (cnt < NUP) ? 1 : 0;
}

// Kernel A2: order-preserving compaction of up nodes -> packed float4{x,y,z,id}.
// One block per batch; chunked Hillis-Steele scan over the mask.
__global__ void compact_kernel(const float* __restrict__ sl, const int* __restrict__ mask,
                               float4* __restrict__ upc) {
    int b = blockIdx.x;
    int tid = threadIdx.x;
    __shared__ int sm[256];
    __shared__ int sbase;
    if (tid == 0) sbase = 0;
    __syncthreads();
    for (int t = 0; t < Nn; t += 256) {
        int node = t + tid;
        int g = b * Nn + node;
        int m = mask[g];
        sm[tid] = m;
        __syncthreads();
        #pragma unroll
        for (int off = 1; off < 256; off <<= 1) {
            int v = (tid >= off) ? sm[tid - off] : 0;
            __syncthreads();
            sm[tid] += v;
            __syncthreads();
        }
        int incl = sm[tid];
        int total = sm[255];
        int base = sbase;
        if (m) {
            float4 c;
            c.x = sl[(size_t)g * 3 + 0];
            c.y = sl[(size_t)g * 3 + 1];
            c.z = sl[(size_t)g * 3 + 2];
            c.w = __int_as_float(node);
            upc[b * NUP + base + incl - 1] = c;
        }
        __syncthreads();
        if (tid == 0) sbase += total;
        __syncthreads();
    }
}

// Kernel B: feat = concat(h, s_l, scores) @ W + b for all rows.
// Down rows -> float feature; up rows -> flipped(-inf) sentinel (0x007FFFFF).
__global__ void feat_kernel(const float* __restrict__ h, const float* __restrict__ sl,
                            const float* __restrict__ sc, const float* __restrict__ W,
                            const float* __restrict__ bias, const int* __restrict__ mask,
                            unsigned* __restrict__ out) {
    int b = blockIdx.y;
    int r0 = blockIdx.x * RPB;
    int tid = threadIdx.x;
    __shared__ float sh[RPB][260];
    const float* hb = h + ((size_t)b * Nn + r0) * Hh;
    #pragma unroll
    for (int r = 0; r < RPB; r++) sh[r][tid] = hb[(size_t)r * Hh + tid];
    if (tid < RPB * 4) {
        int r = tid >> 2, q = tid & 3;
        int node = r0 + r;
        if (q < 3) sh[r][256 + q] = sl[((size_t)b * Nn + node) * 3 + q];
        else       sh[r][259]     = sc[(size_t)b * Nn + node];
    }
    __syncthreads();
    float acc[RPB];
    float bb = bias[tid];
    #pragma unroll
    for (int r = 0; r < RPB; r++) acc[r] = bb;
    for (int k = 0; k < 260; k += 4) {
        float w0 = W[(k + 0) * Hh + tid];
        float w1 = W[(k + 1) * Hh + tid];
        float w2 = W[(k + 2) * Hh + tid];
        float w3 = W[(k + 3) * Hh + tid];
        #pragma unroll
        for (int r = 0; r < RPB; r++) {
            float4 iv = *(const float4*)&sh[r][k];
            acc[r] += iv.x * w0 + iv.y * w1 + iv.z * w2 + iv.w * w3;
        }
    }
    #pragma unroll
    for (int r = 0; r < RPB; r++) {
        int g = b * Nn + r0 + r;
        out[(size_t)g * Hh + tid] = mask[g] ? 0x007FFFFFu : __float_as_uint(acc[r]);
    }
}

// Kernel C: 5-NN over the compacted up set staged once in LDS.
// Candidates scanned in ascending node order; strict '<' insertion matches
// top_k's lower-index-first tie-break.
__global__ void knn_kernel(const float* __restrict__ sl, const int* __restrict__ mask,
                           const float4* __restrict__ upc, int* __restrict__ knn) {
    int b = blockIdx.y;
    int tid = threadIdx.x;
    int i = blockIdx.x * 256 + tid;
    int g = b * Nn + i;
    __shared__ float4 cand[NUP];
    #pragma unroll
    for (int k = 0; k < NUP / 256; k++) cand[k * 256 + tid] = upc[b * NUP + k * 256 + tid];
    __syncthreads();
    if (mask[g]) return;
    float xi = sl[(size_t)g * 3 + 0];
    float yi = sl[(size_t)g * 3 + 1];
    float zi = sl[(size_t)g * 3 + 2];
    float bd[MM];
    int bj[MM];
    #pragma unroll
    for (int m = 0; m < MM; m++) { bd[m] = 3.4e38f; bj[m] = -1; }
    #pragma unroll 4
    for (int jj = 0; jj < NUP; jj++) {
        float4 c = cand[jj];
        float dx = c.x - xi, dy = c.y - yi, dz = c.z - zi;
        float d2 = fmaf(dx, dx, fmaf(dy, dy, dz * dz));
        if (d2 < bd[MM - 1]) {
            float cd = d2; int cj = __float_as_int(c.w);
            #pragma unroll
            for (int p = 0; p < MM; p++) {
                if (cd < bd[p]) {
                    float td = bd[p]; int tj = bj[p];
                    bd[p] = cd; bj[p] = cj;
                    cd = td; cj = tj;
                }
            }
        }
    }
    #pragma unroll
    for (int m = 0; m < MM; m++) knn[g * MM + m] = bj[m];
}

// Kernel D: scatter-max. One block (64 threads) per down node; each lane owns
// 4 columns; 5 atomicMax per owned column into the up rows of d_out.
__global__ void scatter_kernel(const int* __restrict__ mask, const int* __restrict__ knn,
                               unsigned* __restrict__ out) {
    int b = blockIdx.y;
    int node = blockIdx.x;
    int g = b * Nn + node;
    if (mask[g]) return;
    int lane = threadIdx.x;
    unsigned e[4];
    #pragma unroll
    for (int q = 0; q < 4; q++) {
        float f = __uint_as_float(out[(size_t)g * Hh + lane + 64 * q]);
        e[q] = flipf(f);
    }
    int nb[MM];
    #pragma unroll
    for (int m = 0; m < MM; m++) nb[m] = knn[g * MM + m];
    #pragma unroll
    for (int m = 0; m < MM; m++) {
        size_t base = ((size_t)(b * Nn + nb[m])) * Hh;
        #pragma unroll
        for (int q = 0; q < 4; q++) atomicMax(&out[base + lane + 64 * q], e[q]);
    }
}

// Kernel E: decode up rows (sentinel -> 0), zero down rows, write mask tail.
__global__ void finalize_kernel(const int* __restrict__ mask, unsigned* __restrict__ out) {
    int b = blockIdx.y;
    int node = blockIdx.x;
    int g = b * Nn + node;
    int c = threadIdx.x;
    bool up = mask[g] != 0;
    float v = 0.f;
    if (up) {
        unsigned u = out[(size_t)g * Hh + c];
        v = (u == 0x007FFFFFu) ? 0.f : unflip(u);
    }
    ((float*)out)[(size_t)g * Hh + c] = v;
    if (c == 0) ((float*)out)[(size_t)Bb * Nn * Hh + g] = up ? 1.0f : 0.0f;
}

extern "C" void kernel_launch(void* const* d_in, const int* in_sizes, int n_in,
                              void* d_out, int out_size, void* d_ws, size_t ws_size,
                              hipStream_t stream) {
    const float* h    = (const float*)d_in[0];
    const float* sl   = (const float*)d_in[1];
    const float* sc   = (const float*)d_in[2];
    const float* W    = (const float*)d_in[3];
    const float* bias = (const float*)d_in[4];

    char* ws = (char*)d_ws;
    int* mask = (int*)ws;                                   ws += (size_t)Bb * Nn * sizeof(int);
    int* knn  = (int*)ws;                                   ws += (size_t)Bb * Nn * MM * sizeof(int);
    float4* upc = (float4*)ws;                              // B*NUP float4
    unsigned* outu = (unsigned*)d_out;

    dim3 blk(256);
    rank_kernel<<<dim3(Nn / 256, Bb), blk, 0, stream>>>(sc, mask);
    compact_kernel<<<dim3(Bb), blk, 0, stream>>>(sl, mask, upc);
    feat_kernel<<<dim3(Nn / RPB, Bb), blk, 0, stream>>>(h, sl, sc, W, bias, mask, outu);
    knn_kernel<<<dim3(Nn / 256, Bb), blk, 0, stream>>>(sl, mask, upc, knn);
    scatter_kernel<<<dim3(Nn, Bb), dim3(64), 0, stream>>>(mask, knn, outu);
    finalize_kernel<<<dim3(Nn, Bb), blk, 0, stream>>>(mask, outu);
}

// Round 3
// 855.764 us; speedup vs baseline: 1.7314x; 1.1306x over previous
//
#include <hip/hip_runtime.h>

#define Bb 8
#define Nn 8192
#define Hh 256
#define NUP 2048
#define MM 5
#define RPB 16
#define NCH 4
#define CHSZ (NUP / NCH)   // 512 candidates per chunk

// Order-preserving float->uint encoding for atomicMax-based float max.
__device__ __forceinline__ unsigned flipf(float f) {
    unsigned u = __float_as_uint(f);
    return (u & 0x80000000u) ? ~u : (u | 0x80000000u);
}
__device__ __forceinline__ float unflip(unsigned u) {
    unsigned bits = (u & 0x80000000u) ? (u & 0x7FFFFFFFu) : ~u;
    return __uint_as_float(bits);
}

// Kernel A: stable descending rank of scores per batch; up_mask = rank < NUP.
__global__ void rank_kernel(const float* __restrict__ scores, int* __restrict__ mask) {
    int b = blockIdx.y;
    int i = blockIdx.x * 256 + threadIdx.x;
    const float* s = scores + b * Nn;
    float si = s[i];
    __shared__ float tile[256];
    int cnt = 0;
    for (int t = 0; t < Nn; t += 256) {
        __syncthreads();
        tile[threadIdx.x] = s[t + threadIdx.x];
        __syncthreads();
        #pragma unroll 8
        for (int jj = 0; jj < 256; jj++) {
            float sj = tile[jj];
            int j = t + jj;
            cnt += (sj > si || (sj == si && j < i)) ? 1 : 0;
        }
    }
    mask[b * Nn + i] = (cnt < NUP) ? 1 : 0;
}

// Kernel A2: order-preserving compaction of up nodes -> packed float4{x,y,z,id}.
// Ballot-based wave scan, 3 syncs per 256-chunk.
__global__ void compact_kernel(const float* __restrict__ sl, const int* __restrict__ mask,
                               float4* __restrict__ upc) {
    int b = blockIdx.x;
    int tid = threadIdx.x;
    int wv = tid >> 6, ln = tid & 63;
    __shared__ int wsum[4];
    __shared__ int sbase;
    if (tid == 0) sbase = 0;
    __syncthreads();
    for (int t = 0; t < Nn; t += 256) {
        int node = t + tid;
        int g = b * Nn + node;
        int m = mask[g];
        unsigned long long bal = __ballot(m != 0);
        int pre = __popcll(bal & ((1ull << ln) - 1ull));
        if (ln == 0) wsum[wv] = __popcll(bal);
        __syncthreads();
        int base = sbase;
        for (int w2 = 0; w2 < wv; w2++) base += wsum[w2];
        if (m) {
            float4 c;
            c.x = sl[(size_t)g * 3 + 0];
            c.y = sl[(size_t)g * 3 + 1];
            c.z = sl[(size_t)g * 3 + 2];
            c.w = __int_as_float(node);
            upc[b * NUP + base + pre] = c;
        }
        __syncthreads();
        if (tid == 0) sbase += wsum[0] + wsum[1] + wsum[2] + wsum[3];
        __syncthreads();
    }
}

// Kernel B: feat = concat(h, s_l, scores) @ W + b for all rows.
// Down rows -> float feature; up rows -> flipped(-inf) sentinel (0x007FFFFF).
__global__ void feat_kernel(const float* __restrict__ h, const float* __restrict__ sl,
                            const float* __restrict__ sc, const float* __restrict__ W,
                            const float* __restrict__ bias, const int* __restrict__ mask,
                            unsigned* __restrict__ out) {
    int b = blockIdx.y;
    int r0 = blockIdx.x * RPB;
    int tid = threadIdx.x;
    __shared__ float sh[RPB][260];
    const float* hb = h + ((size_t)b * Nn + r0) * Hh;
    #pragma unroll
    for (int r = 0; r < RPB; r++) sh[r][tid] = hb[(size_t)r * Hh + tid];
    if (tid < RPB * 4) {
        int r = tid >> 2, q = tid & 3;
        int node = r0 + r;
        if (q < 3) sh[r][256 + q] = sl[((size_t)b * Nn + node) * 3 + q];
        else       sh[r][259]     = sc[(size_t)b * Nn + node];
    }
    __syncthreads();
    float acc[RPB];
    float bb = bias[tid];
    #pragma unroll
    for (int r = 0; r < RPB; r++) acc[r] = bb;
    for (int k = 0; k < 260; k += 4) {
        float w0 = W[(k + 0) * Hh + tid];
        float w1 = W[(k + 1) * Hh + tid];
        float w2 = W[(k + 2) * Hh + tid];
        float w3 = W[(k + 3) * Hh + tid];
        #pragma unroll
        for (int r = 0; r < RPB; r++) {
            float4 iv = *(const float4*)&sh[r][k];
            acc[r] += iv.x * w0 + iv.y * w1 + iv.z * w2 + iv.w * w3;
        }
    }
    #pragma unroll
    for (int r = 0; r < RPB; r++) {
        int g = b * Nn + r0 + r;
        out[(size_t)g * Hh + tid] = mask[g] ? 0x007FFFFFu : __float_as_uint(acc[r]);
    }
}

// Kernel C1: per-chunk 5-NN. Grid (Nn/256, NCH, Bb). Each block stages 512
// candidates (8 KB LDS) and emits a top-5 (d2, idx) partial list per down node.
__global__ void knn_partial(const float* __restrict__ sl, const int* __restrict__ mask,
                            const float4* __restrict__ upc, uint2* __restrict__ part) {
    int b = blockIdx.z;
    int ch = blockIdx.y;
    int tid = threadIdx.x;
    int i = blockIdx.x * 256 + tid;
    int g = b * Nn + i;
    __shared__ float4 cand[CHSZ];
    cand[tid]       = upc[b * NUP + ch * CHSZ + tid];
    cand[256 + tid] = upc[b * NUP + ch * CHSZ + 256 + tid];
    __syncthreads();
    if (mask[g]) return;
    float xi = sl[(size_t)g * 3 + 0];
    float yi = sl[(size_t)g * 3 + 1];
    float zi = sl[(size_t)g * 3 + 2];
    float bd[MM];
    int bj[MM];
    #pragma unroll
    for (int m = 0; m < MM; m++) { bd[m] = 3.4e38f; bj[m] = 0x7FFFFFFF; }
    #pragma unroll 4
    for (int jj = 0; jj < CHSZ; jj++) {
        float4 c = cand[jj];
        float dx = c.x - xi, dy = c.y - yi, dz = c.z - zi;
        float d2 = fmaf(dx, dx, fmaf(dy, dy, dz * dz));
        if (d2 < bd[MM - 1]) {
            float cd = d2; int cj = __float_as_int(c.w);
            #pragma unroll
            for (int p = 0; p < MM; p++) {
                if (cd < bd[p]) {
                    float td = bd[p]; int tj = bj[p];
                    bd[p] = cd; bj[p] = cj;
                    cd = td; cj = tj;
                }
            }
        }
    }
    #pragma unroll
    for (int m = 0; m < MM; m++) {
        uint2 e; e.x = __float_as_uint(bd[m]); e.y = (unsigned)bj[m];
        part[((size_t)g * NCH + ch) * MM + m] = e;
    }
}

// Kernel C2: lexicographic (d2, idx) merge of NCH partial lists -> final 5-NN.
// Bottom-5 under lex order == sequential strict-'<' scan result.
__global__ void knn_merge(const int* __restrict__ mask, const uint2* __restrict__ part,
                          int* __restrict__ knn) {
    int b = blockIdx.y;
    int i = blockIdx.x * 256 + threadIdx.x;
    int g = b * Nn + i;
    if (mask[g]) return;
    float bd[MM];
    int bj[MM];
    #pragma unroll
    for (int m = 0; m < MM; m++) { bd[m] = 3.4e38f; bj[m] = 0x7FFFFFFF; }
    #pragma unroll
    for (int ch = 0; ch < NCH; ch++) {
        #pragma unroll
        for (int m = 0; m < MM; m++) {
            uint2 e = part[((size_t)g * NCH + ch) * MM + m];
            float cd = __uint_as_float(e.x);
            int cj = (int)e.y;
            #pragma unroll
            for (int p = 0; p < MM; p++) {
                if (cd < bd[p] || (cd == bd[p] && cj < bj[p])) {
                    float td = bd[p]; int tj = bj[p];
                    bd[p] = cd; bj[p] = cj;
                    cd = td; cj = tj;
                }
            }
        }
    }
    #pragma unroll
    for (int m = 0; m < MM; m++) knn[g * MM + m] = bj[m];
}

// Kernel D: scatter-max. One block (64 threads) per down node; each lane owns
// 4 columns; 5 atomicMax per owned column into the up rows of d_out.
__global__ void scatter_kernel(const int* __restrict__ mask, const int* __restrict__ knn,
                               unsigned* __restrict__ out) {
    int b = blockIdx.y;
    int node = blockIdx.x;
    int g = b * Nn + node;
    if (mask[g]) return;
    int lane = threadIdx.x;
    unsigned e[4];
    #pragma unroll
    for (int q = 0; q < 4; q++) {
        float f = __uint_as_float(out[(size_t)g * Hh + lane + 64 * q]);
        e[q] = flipf(f);
    }
    int nb[MM];
    #pragma unroll
    for (int m = 0; m < MM; m++) nb[m] = knn[g * MM + m];
    #pragma unroll
    for (int m = 0; m < MM; m++) {
        size_t base = ((size_t)(b * Nn + nb[m])) * Hh;
        #pragma unroll
        for (int q = 0; q < 4; q++) atomicMax(&out[base + lane + 64 * q], e[q]);
    }
}

// Kernel E: decode up rows (sentinel -> 0), zero down rows, write mask tail.
__global__ void finalize_kernel(const int* __restrict__ mask, unsigned* __restrict__ out) {
    int b = blockIdx.y;
    int node = blockIdx.x;
    int g = b * Nn + node;
    int c = threadIdx.x;
    bool up = mask[g] != 0;
    float v = 0.f;
    if (up) {
        unsigned u = out[(size_t)g * Hh + c];
        v = (u == 0x007FFFFFu) ? 0.f : unflip(u);
    }
    ((float*)out)[(size_t)g * Hh + c] = v;
    if (c == 0) ((float*)out)[(size_t)Bb * Nn * Hh + g] = up ? 1.0f : 0.0f;
}

extern "C" void kernel_launch(void* const* d_in, const int* in_sizes, int n_in,
                              void* d_out, int out_size, void* d_ws, size_t ws_size,
                              hipStream_t stream) {
    const float* h    = (const float*)d_in[0];
    const float* sl   = (const float*)d_in[1];
    const float* sc   = (const float*)d_in[2];
    const float* W    = (const float*)d_in[3];
    const float* bias = (const float*)d_in[4];

    char* ws = (char*)d_ws;
    int* mask = (int*)ws;                                   ws += (size_t)Bb * Nn * sizeof(int);
    int* knn  = (int*)ws;                                   ws += (size_t)Bb * Nn * MM * sizeof(int);
    float4* upc = (float4*)ws;                              // B*NUP float4
    unsigned* outu = (unsigned*)d_out;
    // Pre-feat scratch: partial KNN lists live in d_out (10.5 MB of 67 MB);
    // feat_kernel overwrites the region afterwards.
    uint2* part = (uint2*)d_out;

    dim3 blk(256);
    rank_kernel<<<dim3(Nn / 256, Bb), blk, 0, stream>>>(sc, mask);
    compact_kernel<<<dim3(Bb), blk, 0, stream>>>(sl, mask, upc);
    knn_partial<<<dim3(Nn / 256, NCH, Bb), blk, 0, stream>>>(sl, mask, upc, part);
    knn_merge<<<dim3(Nn / 256, Bb), blk, 0, stream>>>(mask, part, knn);
    feat_kernel<<<dim3(Nn / RPB, Bb), blk, 0, stream>>>(h, sl, sc, W, bias, mask, outu);
    scatter_kernel<<<dim3(Nn, Bb), dim3(64), 0, stream>>>(mask, knn, outu);
    finalize_kernel<<<dim3(Nn, Bb), blk, 0, stream>>>(mask, outu);
}

// Round 4
// 716.771 us; speedup vs baseline: 2.0671x; 1.1939x over previous
//
#include <hip/hip_runtime.h>

#define Bb 8
#define Nn 8192
#define Hh 256
#define NUP 2048
#define MM 5
#define NCH 4
#define CHSZ (NUP / NCH)   // 512 candidates per chunk
#define KP 288             // padded K for the feat GEMM (256 h + sl,score,1,pad)
#define LDA 36             // LDS row stride (bf16) for A/B tiles: 72B = 18 banks

typedef short v8s __attribute__((ext_vector_type(8)));
typedef float v4f __attribute__((ext_vector_type(4)));

#define SENT 0x007FFFFFu   // flipf(-inf)

// Order-preserving float->uint encoding for atomicMax-based float max.
__device__ __forceinline__ unsigned flipf(float f) {
    unsigned u = __float_as_uint(f);
    return (u & 0x80000000u) ? ~u : (u | 0x80000000u);
}
__device__ __forceinline__ float unflip(unsigned u) {
    unsigned bits = (u & 0x80000000u) ? (u & 0x7FFFFFFFu) : ~u;
    return __uint_as_float(bits);
}
// fp32 -> bf16 round-to-nearest-even
__device__ __forceinline__ unsigned short bfc(float f) {
    unsigned u = __float_as_uint(f);
    return (unsigned short)((u + 0x7FFFu + ((u >> 16) & 1u)) >> 16);
}

// Kernel A: stable descending rank of scores per batch; up_mask = rank < NUP.
__global__ void rank_kernel(const float* __restrict__ scores, int* __restrict__ mask) {
    int b = blockIdx.y;
    int i = blockIdx.x * 256 + threadIdx.x;
    const float* s = scores + b * Nn;
    float si = s[i];
    __shared__ float tile[256];
    int cnt = 0;
    for (int t = 0; t < Nn; t += 256) {
        __syncthreads();
        tile[threadIdx.x] = s[t + threadIdx.x];
        __syncthreads();
        #pragma unroll 8
        for (int jj = 0; jj < 256; jj++) {
            float sj = tile[jj];
            int j = t + jj;
            cnt += (sj > si || (sj == si && j < i)) ? 1 : 0;
        }
    }
    mask[b * Nn + i] = (cnt < NUP) ? 1 : 0;
}

// Kernel A2: order-preserving compaction of up nodes -> packed float4{x,y,z,id}.
__global__ void compact_kernel(const float* __restrict__ sl, const int* __restrict__ mask,
                               float4* __restrict__ upc) {
    int b = blockIdx.x;
    int tid = threadIdx.x;
    int wv = tid >> 6, ln = tid & 63;
    __shared__ int wsum[4];
    __shared__ int sbase;
    if (tid == 0) sbase = 0;
    __syncthreads();
    for (int t = 0; t < Nn; t += 256) {
        int node = t + tid;
        int g = b * Nn + node;
        int m = mask[g];
        unsigned long long bal = __ballot(m != 0);
        int pre = __popcll(bal & ((1ull << ln) - 1ull));
        if (ln == 0) wsum[wv] = __popcll(bal);
        __syncthreads();
        int base = sbase;
        for (int w2 = 0; w2 < wv; w2++) base += wsum[w2];
        if (m) {
            float4 c;
            c.x = sl[(size_t)g * 3 + 0];
            c.y = sl[(size_t)g * 3 + 1];
            c.z = sl[(size_t)g * 3 + 2];
            c.w = __int_as_float(node);
            upc[b * NUP + base + pre] = c;
        }
        __syncthreads();
        if (tid == 0) sbase += wsum[0] + wsum[1] + wsum[2] + wsum[3];
        __syncthreads();
    }
}

// Kernel W: Wt[n][k] = bf16 of W-ext^T: k<260 -> W[k][n]; k==260 -> bias[n]; else 0.
__global__ void wt_kernel(const float* __restrict__ W, const float* __restrict__ bias,
                          unsigned short* __restrict__ Wt) {
    int n = blockIdx.x;
    int k = threadIdx.x;
    Wt[n * KP + k] = bfc(W[(size_t)k * Hh + n]);
    if (k < KP - 256) {
        int kk = 256 + k;
        unsigned short v = 0;
        if (kk < 260)       v = bfc(W[(size_t)kk * Hh + n]);
        else if (kk == 260) v = bfc(bias[n]);
        Wt[n * KP + kk] = v;
    }
}

// Kernel B: feat GEMM via bf16 MFMA. C[128m x 128n] per block, 4 waves of 64x64.
// A-ext = [h | sl, score, 1, 0...] (K=288), B = Wt (pre-transposed bf16).
// Down rows -> float bits; up rows -> SENT sentinel. Written to d_out.
__global__ void feat_mfma(const float* __restrict__ h, const float* __restrict__ sl,
                          const float* __restrict__ sc, const unsigned short* __restrict__ Wt,
                          const int* __restrict__ mask, unsigned* __restrict__ out) {
    int b = blockIdx.z;
    int m0 = blockIdx.x * 128;
    int n0 = blockIdx.y * 128;
    int tid = threadIdx.x;
    __shared__ unsigned short Al[128 * LDA];
    __shared__ unsigned short Bl[128 * LDA];
    int wid = tid >> 6, lane = tid & 63;
    int wm = (wid & 1) * 64, wn = (wid >> 1) * 64;
    int lm = lane & 15, quad = lane >> 4;
    v4f acc[4][4];
    #pragma unroll
    for (int i = 0; i < 4; i++)
        #pragma unroll
        for (int j = 0; j < 4; j++)
            acc[i][j] = (v4f){0.f, 0.f, 0.f, 0.f};
    const float* Ab = h + ((size_t)b * Nn + m0) * Hh;
    for (int t = 0; t < 9; t++) {
        int k0 = t * 32;
        __syncthreads();
        if (t < 8) {
            #pragma unroll
            for (int q = 0; q < 4; q++) {
                int e = q * 256 + tid;
                int row = e >> 3, kq = e & 7;
                float4 v = *(const float4*)(Ab + (size_t)row * Hh + k0 + kq * 4);
                ushort4 o = make_ushort4(bfc(v.x), bfc(v.y), bfc(v.z), bfc(v.w));
                *(ushort4*)(Al + row * LDA + kq * 4) = o;
            }
        } else if (tid < 128) {
            int row = tid;
            int g = b * Nn + m0 + row;
            unsigned short r[32];
            #pragma unroll
            for (int k = 0; k < 32; k++) r[k] = 0;
            r[0] = bfc(sl[(size_t)g * 3 + 0]);
            r[1] = bfc(sl[(size_t)g * 3 + 1]);
            r[2] = bfc(sl[(size_t)g * 3 + 2]);
            r[3] = bfc(sc[g]);
            r[4] = 0x3F80;  // 1.0 in bf16 (bias column)
            #pragma unroll
            for (int q = 0; q < 8; q++)
                *(ushort4*)(Al + row * LDA + q * 4) =
                    make_ushort4(r[q * 4], r[q * 4 + 1], r[q * 4 + 2], r[q * 4 + 3]);
        }
        #pragma unroll
        for (int q = 0; q < 4; q++) {
            int e = q * 256 + tid;
            int n = e >> 3, kq = e & 7;
            ushort4 v = *(const ushort4*)(Wt + (size_t)(n0 + n) * KP + k0 + kq * 4);
            *(ushort4*)(Bl + n * LDA + kq * 4) = v;
        }
        __syncthreads();
        v8s af[4], bfr[4];
        #pragma unroll
        for (int i = 0; i < 4; i++)
            af[i] = *(const v8s*)(Al + (wm + i * 16 + lm) * LDA + quad * 8);
        #pragma unroll
        for (int j = 0; j < 4; j++)
            bfr[j] = *(const v8s*)(Bl + (wn + j * 16 + lm) * LDA + quad * 8);
        #pragma unroll
        for (int i = 0; i < 4; i++)
            #pragma unroll
            for (int j = 0; j < 4; j++)
                acc[i][j] = __builtin_amdgcn_mfma_f32_16x16x32_bf16(af[i], bfr[j], acc[i][j], 0, 0, 0);
    }
    // Epilogue: C/D layout col=lane&15, row=quad*4+reg.
    #pragma unroll
    for (int i = 0; i < 4; i++) {
        #pragma unroll
        for (int r = 0; r < 4; r++) {
            int row = m0 + wm + i * 16 + quad * 4 + r;
            int g = b * Nn + row;
            bool up = mask[g] != 0;
            size_t base = (size_t)g * Hh + n0 + wn + lm;
            #pragma unroll
            for (int j = 0; j < 4; j++)
                out[base + j * 16] = up ? SENT : __float_as_uint(acc[i][j][r]);
        }
    }
}

// Kernel C1: per-chunk 5-NN. Grid (Nn/256, NCH, Bb).
__global__ void knn_partial(const float* __restrict__ sl, const int* __restrict__ mask,
                            const float4* __restrict__ upc, uint2* __restrict__ part) {
    int b = blockIdx.z;
    int ch = blockIdx.y;
    int tid = threadIdx.x;
    int i = blockIdx.x * 256 + tid;
    int g = b * Nn + i;
    __shared__ float4 cand[CHSZ];
    cand[tid]       = upc[b * NUP + ch * CHSZ + tid];
    cand[256 + tid] = upc[b * NUP + ch * CHSZ + 256 + tid];
    __syncthreads();
    if (mask[g]) return;
    float xi = sl[(size_t)g * 3 + 0];
    float yi = sl[(size_t)g * 3 + 1];
    float zi = sl[(size_t)g * 3 + 2];
    float bd[MM];
    int bj[MM];
    #pragma unroll
    for (int m = 0; m < MM; m++) { bd[m] = 3.4e38f; bj[m] = 0x7FFFFFFF; }
    #pragma unroll 4
    for (int jj = 0; jj < CHSZ; jj++) {
        float4 c = cand[jj];
        float dx = c.x - xi, dy = c.y - yi, dz = c.z - zi;
        float d2 = fmaf(dx, dx, fmaf(dy, dy, dz * dz));
        if (d2 < bd[MM - 1]) {
            float cd = d2; int cj = __float_as_int(c.w);
            #pragma unroll
            for (int p = 0; p < MM; p++) {
                if (cd < bd[p]) {
                    float td = bd[p]; int tj = bj[p];
                    bd[p] = cd; bj[p] = cj;
                    cd = td; cj = tj;
                }
            }
        }
    }
    #pragma unroll
    for (int m = 0; m < MM; m++) {
        uint2 e; e.x = __float_as_uint(bd[m]); e.y = (unsigned)bj[m];
        part[((size_t)g * NCH + ch) * MM + m] = e;
    }
}

// Kernel C2: lexicographic (d2, idx) merge of NCH partial lists -> final 5-NN.
__global__ void knn_merge(const int* __restrict__ mask, const uint2* __restrict__ part,
                          int* __restrict__ knn) {
    int b = blockIdx.y;
    int i = blockIdx.x * 256 + threadIdx.x;
    int g = b * Nn + i;
    if (mask[g]) return;
    float bd[MM];
    int bj[MM];
    #pragma unroll
    for (int m = 0; m < MM; m++) { bd[m] = 3.4e38f; bj[m] = 0x7FFFFFFF; }
    #pragma unroll
    for (int ch = 0; ch < NCH; ch++) {
        #pragma unroll
        for (int m = 0; m < MM; m++) {
            uint2 e = part[((size_t)g * NCH + ch) * MM + m];
            float cd = __uint_as_float(e.x);
            int cj = (int)e.y;
            #pragma unroll
            for (int p = 0; p < MM; p++) {
                if (cd < bd[p] || (cd == bd[p] && cj < bj[p])) {
                    float td = bd[p]; int tj = bj[p];
                    bd[p] = cd; bj[p] = cj;
                    cd = td; cj = tj;
                }
            }
        }
    }
    #pragma unroll
    for (int m = 0; m < MM; m++) knn[g * MM + m] = bj[m];
}

// Kernel D: scatter-max. Wave-per-down-node (4 nodes per 256-thread block).
__global__ void scatter_kernel(const int* __restrict__ mask, const int* __restrict__ knn,
                               unsigned* __restrict__ out) {
    int b = blockIdx.y;
    int node = blockIdx.x * 4 + (threadIdx.x >> 6);
    int g = b * Nn + node;
    if (mask[g]) return;
    int lane = threadIdx.x & 63;
    unsigned e[4];
    #pragma unroll
    for (int q = 0; q < 4; q++) {
        float f = __uint_as_float(out[(size_t)g * Hh + lane + 64 * q]);
        e[q] = flipf(f);
    }
    int nb[MM];
    #pragma unroll
    for (int m = 0; m < MM; m++) nb[m] = knn[g * MM + m];
    #pragma unroll
    for (int m = 0; m < MM; m++) {
        size_t base = ((size_t)(b * Nn + nb[m])) * Hh;
        #pragma unroll
        for (int q = 0; q < 4; q++) atomicMax(&out[base + lane + 64 * q], e[q]);
    }
}

// Kernel E: decode up rows (sentinel -> 0), zero down rows, write mask tail.
__global__ void finalize_kernel(const int* __restrict__ mask, unsigned* __restrict__ out) {
    int b = blockIdx.y;
    int node = blockIdx.x * 4 + (threadIdx.x >> 6);
    int g = b * Nn + node;
    int lane = threadIdx.x & 63;
    bool up = mask[g] != 0;
    uint4* rowp = (uint4*)(out + (size_t)g * Hh) + lane;
    float4 v = make_float4(0.f, 0.f, 0.f, 0.f);
    if (up) {
        uint4 u = *rowp;
        v.x = (u.x == SENT) ? 0.f : unflip(u.x);
        v.y = (u.y == SENT) ? 0.f : unflip(u.y);
        v.z = (u.z == SENT) ? 0.f : unflip(u.z);
        v.w = (u.w == SENT) ? 0.f : unflip(u.w);
    }
    *(float4*)rowp = v;
    if (lane == 0) ((float*)out)[(size_t)Bb * Nn * Hh + g] = up ? 1.0f : 0.0f;
}

extern "C" void kernel_launch(void* const* d_in, const int* in_sizes, int n_in,
                              void* d_out, int out_size, void* d_ws, size_t ws_size,
                              hipStream_t stream) {
    const float* h    = (const float*)d_in[0];
    const float* sl   = (const float*)d_in[1];
    const float* sc   = (const float*)d_in[2];
    const float* W    = (const float*)d_in[3];
    const float* bias = (const float*)d_in[4];

    char* ws = (char*)d_ws;
    int* mask = (int*)ws;                 ws += (size_t)Bb * Nn * sizeof(int);
    int* knn  = (int*)ws;                 ws += (size_t)Bb * Nn * MM * sizeof(int);
    float4* upc = (float4*)ws;            ws += (size_t)Bb * NUP * sizeof(float4);
    unsigned short* Wt = (unsigned short*)ws;  // 256*KP bf16
    unsigned* outu = (unsigned*)d_out;
    // Pre-feat scratch: partial KNN lists live in d_out (10.5 MB of 67 MB);
    // feat_mfma overwrites the region afterwards.
    uint2* part = (uint2*)d_out;

    dim3 blk(256);
    rank_kernel<<<dim3(Nn / 256, Bb), blk, 0, stream>>>(sc, mask);
    compact_kernel<<<dim3(Bb), blk, 0, stream>>>(sl, mask, upc);
    wt_kernel<<<dim3(Hh), blk, 0, stream>>>(W, bias, Wt);
    knn_partial<<<dim3(Nn / 256, NCH, Bb), blk, 0, stream>>>(sl, mask, upc, part);
    knn_merge<<<dim3(Nn / 256, Bb), blk, 0, stream>>>(mask, part, knn);
    feat_mfma<<<dim3(Nn / 128, 2, Bb), blk, 0, stream>>>(h, sl, sc, Wt, mask, outu);
    scatter_kernel<<<dim3(Nn / 4, Bb), blk, 0, stream>>>(mask, knn, outu);
    finalize_kernel<<<dim3(Nn / 4, Bb), blk, 0, stream>>>(mask, outu);
}

// Round 5
// 509.325 us; speedup vs baseline: 2.9091x; 1.4073x over previous
//
#include <hip/hip_runtime.h>

#define Bb 8
#define Nn 8192
#define Hh 256
#define NUP 2048
#define MM 5
#define NCH 4
#define CHSZ (NUP / NCH)   // 512 candidates per chunk
#define KP 288             // padded K for the feat GEMM (256 h + sl,score,1,pad)
#define LDA 36             // LDS row stride (bf16) for A/B tiles

typedef short v8s __attribute__((ext_vector_type(8)));
typedef float v4f __attribute__((ext_vector_type(4)));

#define SENT 0x007FFFFFu   // flipf(-inf)

__device__ __forceinline__ unsigned flipf(float f) {
    unsigned u = __float_as_uint(f);
    return (u & 0x80000000u) ? ~u : (u | 0x80000000u);
}
__device__ __forceinline__ float unflip(unsigned u) {
    unsigned bits = (u & 0x80000000u) ? (u & 0x7FFFFFFFu) : ~u;
    return __uint_as_float(bits);
}
// fp32 -> bf16 round-to-nearest-even
__device__ __forceinline__ unsigned short bfc(float f) {
    unsigned u = __float_as_uint(f);
    return (unsigned short)((u + 0x7FFFu + ((u >> 16) & 1u)) >> 16);
}

// Find the bin (descending order) where the kth-largest element lands.
// hist has NB bins; each of 1024 threads owns NB/1024 consecutive descending bins.
// Returns bin and count of elements in strictly higher bins.
template <int NB>
__device__ void find_kth_bin(const int* hist, int kth, int tid,
                             int* wsumA, int* res, int* out_bin, int* out_cntgt) {
    constexpr int PER = NB / 1024;
    int ln = tid & 63, wv = tid >> 6;
    int b0 = NB - 1 - PER * tid;
    int c0 = hist[b0];
    int c1 = (PER == 2) ? hist[b0 - 1] : 0;
    int tot = c0 + c1;
    int x = tot;
    #pragma unroll
    for (int off = 1; off < 64; off <<= 1) {
        int y = __shfl_up(x, off);
        if (ln >= off) x += y;
    }
    if (ln == 63) wsumA[wv] = x;
    __syncthreads();
    int wbase = 0;
    for (int w = 0; w < wv; w++) wbase += wsumA[w];
    int excl = wbase + x - tot;          // elements in bins above b0
    if (excl < kth && excl + c0 >= kth) { res[0] = b0; res[1] = excl; }
    else if (PER == 2 && excl + c0 < kth && excl + c0 + c1 >= kth) { res[0] = b0 - 1; res[1] = excl + c0; }
    __syncthreads();
    *out_bin = res[0];
    *out_cntgt = res[1];
}

// Kernel A: exact top-NUP selection by (score desc, index asc) via 3-level
// radix select on the uint pattern (scores >= 0), fused with order-preserving
// compaction of up-node coords. One 1024-thread block per batch.
__global__ __launch_bounds__(1024) void select_kernel(
        const float* __restrict__ scores, const float* __restrict__ sl,
        int* __restrict__ mask, float4* __restrict__ upc) {
    int b = blockIdx.x;
    int tid = threadIdx.x;
    int ln = tid & 63, wv = tid >> 6;
    __shared__ int hist[2048];
    __shared__ int wsumA[16], wsumB[16];
    __shared__ int res[2];
    __shared__ int sbase[2];             // running eq / up counts
    const float* s = scores + (size_t)b * Nn;

    // ---- pass 1: bits [31:21] (2048 bins)
    hist[tid] = 0; hist[tid + 1024] = 0;
    __syncthreads();
    for (int t = tid; t < Nn; t += 1024)
        atomicAdd(&hist[__float_as_uint(s[t]) >> 21], 1);
    __syncthreads();
    int B1, gt1;
    find_kth_bin<2048>(hist, NUP, tid, wsumA, res, &B1, &gt1);
    int slots1 = NUP - gt1;

    // ---- pass 2: bits [20:10] among top11 == B1
    hist[tid] = 0; hist[tid + 1024] = 0;
    __syncthreads();
    for (int t = tid; t < Nn; t += 1024) {
        unsigned u = __float_as_uint(s[t]);
        if ((int)(u >> 21) == B1) atomicAdd(&hist[(u >> 10) & 0x7FF], 1);
    }
    __syncthreads();
    int B2, gt2;
    find_kth_bin<2048>(hist, slots1, tid, wsumA, res, &B2, &gt2);
    int slots2 = slots1 - gt2;
    unsigned hi22 = ((unsigned)B1 << 11) | (unsigned)B2;

    // ---- pass 3: bits [9:0] among top22 == hi22
    hist[tid] = 0; hist[tid + 1024] = 0;
    __syncthreads();
    for (int t = tid; t < Nn; t += 1024) {
        unsigned u = __float_as_uint(s[t]);
        if ((u >> 10) == hi22) atomicAdd(&hist[u & 0x3FF], 1);
    }
    __syncthreads();
    int B3, gt3;
    find_kth_bin<1024>(hist, slots2, tid, wsumA, res, &B3, &gt3);
    int slots_eq = slots2 - gt3;         // T-valued elements to accept (>=1)
    unsigned T = (hi22 << 10) | (unsigned)B3;

    // ---- final pass: mask + compaction, index order, ballot scans
    if (tid == 0) { sbase[0] = 0; sbase[1] = 0; }
    __syncthreads();
    for (int t0 = 0; t0 < Nn; t0 += 1024) {
        int node = t0 + tid;
        int g = b * Nn + node;
        unsigned u = __float_as_uint(s[node]);
        bool eq = (u == T);
        unsigned long long bal = __ballot(eq);
        unsigned long long lmask = (1ull << ln) - 1ull;
        int pre = __popcll(bal & lmask);
        if (ln == 0) wsumA[wv] = __popcll(bal);
        __syncthreads();
        int eqbase = sbase[0];
        for (int w = 0; w < wv; w++) eqbase += wsumA[w];
        bool up = (u > T) || (eq && (eqbase + pre) < slots_eq);
        unsigned long long bal2 = __ballot(up);
        int pre2 = __popcll(bal2 & lmask);
        if (ln == 0) wsumB[wv] = __popcll(bal2);
        __syncthreads();
        int upbase = sbase[1];
        for (int w = 0; w < wv; w++) upbase += wsumB[w];
        if (up) {
            float4 c;
            c.x = sl[(size_t)g * 3 + 0];
            c.y = sl[(size_t)g * 3 + 1];
            c.z = sl[(size_t)g * 3 + 2];
            c.w = __int_as_float(node);
            upc[b * NUP + upbase + pre2] = c;
        }
        mask[g] = up ? 1 : 0;
        __syncthreads();
        if (tid == 0) {
            int se = 0, su = 0;
            for (int w = 0; w < 16; w++) { se += wsumA[w]; su += wsumB[w]; }
            sbase[0] += se; sbase[1] += su;
        }
        __syncthreads();
    }
}

// Kernel W: Wt[n][k] = bf16 of W-ext^T: k<260 -> W[k][n]; k==260 -> bias[n]; else 0.
__global__ void wt_kernel(const float* __restrict__ W, const float* __restrict__ bias,
                          unsigned short* __restrict__ Wt) {
    int n = blockIdx.x;
    int k = threadIdx.x;
    Wt[n * KP + k] = bfc(W[(size_t)k * Hh + n]);
    if (k < KP - 256) {
        int kk = 256 + k;
        unsigned short v = 0;
        if (kk < 260)       v = bfc(W[(size_t)kk * Hh + n]);
        else if (kk == 260) v = bfc(bias[n]);
        Wt[n * KP + kk] = v;
    }
}

// Kernel B: feat GEMM via bf16 MFMA. C[128m x 128n] per block, 4 waves of 64x64.
__global__ void feat_mfma(const float* __restrict__ h, const float* __restrict__ sl,
                          const float* __restrict__ sc, const unsigned short* __restrict__ Wt,
                          const int* __restrict__ mask, unsigned* __restrict__ out) {
    int b = blockIdx.z;
    int m0 = blockIdx.x * 128;
    int n0 = blockIdx.y * 128;
    int tid = threadIdx.x;
    __shared__ unsigned short Al[128 * LDA];
    __shared__ unsigned short Bl[128 * LDA];
    int wid = tid >> 6, lane = tid & 63;
    int wm = (wid & 1) * 64, wn = (wid >> 1) * 64;
    int lm = lane & 15, quad = lane >> 4;
    v4f acc[4][4];
    #pragma unroll
    for (int i = 0; i < 4; i++)
        #pragma unroll
        for (int j = 0; j < 4; j++)
            acc[i][j] = (v4f){0.f, 0.f, 0.f, 0.f};
    const float* Ab = h + ((size_t)b * Nn + m0) * Hh;
    for (int t = 0; t < 9; t++) {
        int k0 = t * 32;
        __syncthreads();
        if (t < 8) {
            #pragma unroll
            for (int q = 0; q < 4; q++) {
                int e = q * 256 + tid;
                int row = e >> 3, kq = e & 7;
                float4 v = *(const float4*)(Ab + (size_t)row * Hh + k0 + kq * 4);
                ushort4 o = make_ushort4(bfc(v.x), bfc(v.y), bfc(v.z), bfc(v.w));
                *(ushort4*)(Al + row * LDA + kq * 4) = o;
            }
        } else if (tid < 128) {
            int row = tid;
            int g = b * Nn + m0 + row;
            unsigned short r[32];
            #pragma unroll
            for (int k = 0; k < 32; k++) r[k] = 0;
            r[0] = bfc(sl[(size_t)g * 3 + 0]);
            r[1] = bfc(sl[(size_t)g * 3 + 1]);
            r[2] = bfc(sl[(size_t)g * 3 + 2]);
            r[3] = bfc(sc[g]);
            r[4] = 0x3F80;  // 1.0 (bias column)
            #pragma unroll
            for (int q = 0; q < 8; q++)
                *(ushort4*)(Al + row * LDA + q * 4) =
                    make_ushort4(r[q * 4], r[q * 4 + 1], r[q * 4 + 2], r[q * 4 + 3]);
        }
        #pragma unroll
        for (int q = 0; q < 4; q++) {
            int e = q * 256 + tid;
            int n = e >> 3, kq = e & 7;
            ushort4 v = *(const ushort4*)(Wt + (size_t)(n0 + n) * KP + k0 + kq * 4);
            *(ushort4*)(Bl + n * LDA + kq * 4) = v;
        }
        __syncthreads();
        v8s af[4], bfr[4];
        #pragma unroll
        for (int i = 0; i < 4; i++)
            af[i] = *(const v8s*)(Al + (wm + i * 16 + lm) * LDA + quad * 8);
        #pragma unroll
        for (int j = 0; j < 4; j++)
            bfr[j] = *(const v8s*)(Bl + (wn + j * 16 + lm) * LDA + quad * 8);
        #pragma unroll
        for (int i = 0; i < 4; i++)
            #pragma unroll
            for (int j = 0; j < 4; j++)
                acc[i][j] = __builtin_amdgcn_mfma_f32_16x16x32_bf16(af[i], bfr[j], acc[i][j], 0, 0, 0);
    }
    #pragma unroll
    for (int i = 0; i < 4; i++) {
        #pragma unroll
        for (int r = 0; r < 4; r++) {
            int row = m0 + wm + i * 16 + quad * 4 + r;
            int g = b * Nn + row;
            bool up = mask[g] != 0;
            size_t base = (size_t)g * Hh + n0 + wn + lm;
            #pragma unroll
            for (int j = 0; j < 4; j++)
                out[base + j * 16] = up ? SENT : __float_as_uint(acc[i][j][r]);
        }
    }
}

// Kernel C1: per-chunk 5-NN. Grid (Nn/256, NCH, Bb).
__global__ void knn_partial(const float* __restrict__ sl, const int* __restrict__ mask,
                            const float4* __restrict__ upc, uint2* __restrict__ part) {
    int b = blockIdx.z;
    int ch = blockIdx.y;
    int tid = threadIdx.x;
    int i = blockIdx.x * 256 + tid;
    int g = b * Nn + i;
    __shared__ float4 cand[CHSZ];
    cand[tid]       = upc[b * NUP + ch * CHSZ + tid];
    cand[256 + tid] = upc[b * NUP + ch * CHSZ + 256 + tid];
    __syncthreads();
    if (mask[g]) return;
    float xi = sl[(size_t)g * 3 + 0];
    float yi = sl[(size_t)g * 3 + 1];
    float zi = sl[(size_t)g * 3 + 2];
    float bd[MM];
    int bj[MM];
    #pragma unroll
    for (int m = 0; m < MM; m++) { bd[m] = 3.4e38f; bj[m] = 0x7FFFFFFF; }
    #pragma unroll 4
    for (int jj = 0; jj < CHSZ; jj++) {
        float4 c = cand[jj];
        float dx = c.x - xi, dy = c.y - yi, dz = c.z - zi;
        float d2 = fmaf(dx, dx, fmaf(dy, dy, dz * dz));
        if (d2 < bd[MM - 1]) {
            float cd = d2; int cj = __float_as_int(c.w);
            #pragma unroll
            for (int p = 0; p < MM; p++) {
                if (cd < bd[p]) {
                    float td = bd[p]; int tj = bj[p];
                    bd[p] = cd; bj[p] = cj;
                    cd = td; cj = tj;
                }
            }
        }
    }
    #pragma unroll
    for (int m = 0; m < MM; m++) {
        uint2 e; e.x = __float_as_uint(bd[m]); e.y = (unsigned)bj[m];
        part[((size_t)g * NCH + ch) * MM + m] = e;
    }
}

// Kernel C2: lexicographic (d2, idx) merge of NCH partial lists -> final 5-NN.
__global__ void knn_merge(const int* __restrict__ mask, const uint2* __restrict__ part,
                          int* __restrict__ knn) {
    int b = blockIdx.y;
    int i = blockIdx.x * 256 + threadIdx.x;
    int g = b * Nn + i;
    if (mask[g]) return;
    float bd[MM];
    int bj[MM];
    #pragma unroll
    for (int m = 0; m < MM; m++) { bd[m] = 3.4e38f; bj[m] = 0x7FFFFFFF; }
    #pragma unroll
    for (int ch = 0; ch < NCH; ch++) {
        #pragma unroll
        for (int m = 0; m < MM; m++) {
            uint2 e = part[((size_t)g * NCH + ch) * MM + m];
            float cd = __uint_as_float(e.x);
            int cj = (int)e.y;
            #pragma unroll
            for (int p = 0; p < MM; p++) {
                if (cd < bd[p] || (cd == bd[p] && cj < bj[p])) {
                    float td = bd[p]; int tj = bj[p];
                    bd[p] = cd; bj[p] = cj;
                    cd = td; cj = tj;
                }
            }
        }
    }
    #pragma unroll
    for (int m = 0; m < MM; m++) knn[g * MM + m] = bj[m];
}

// Kernel D: scatter-max. Wave-per-down-node (4 nodes per 256-thread block).
__global__ void scatter_kernel(const int* __restrict__ mask, const int* __restrict__ knn,
                               unsigned* __restrict__ out) {
    int b = blockIdx.y;
    int node = blockIdx.x * 4 + (threadIdx.x >> 6);
    int g = b * Nn + node;
    if (mask[g]) return;
    int lane = threadIdx.x & 63;
    unsigned e[4];
    #pragma unroll
    for (int q = 0; q < 4; q++) {
        float f = __uint_as_float(out[(size_t)g * Hh + lane + 64 * q]);
        e[q] = flipf(f);
    }
    int nb[MM];
    #pragma unroll
    for (int m = 0; m < MM; m++) nb[m] = knn[g * MM + m];
    #pragma unroll
    for (int m = 0; m < MM; m++) {
        size_t base = ((size_t)(b * Nn + nb[m])) * Hh;
        #pragma unroll
        for (int q = 0; q < 4; q++) atomicMax(&out[base + lane + 64 * q], e[q]);
    }
}

// Kernel E: decode up rows (sentinel -> 0), zero down rows, write mask tail.
__global__ void finalize_kernel(const int* __restrict__ mask, unsigned* __restrict__ out) {
    int b = blockIdx.y;
    int node = blockIdx.x * 4 + (threadIdx.x >> 6);
    int g = b * Nn + node;
    int lane = threadIdx.x & 63;
    bool up = mask[g] != 0;
    uint4* rowp = (uint4*)(out + (size_t)g * Hh) + lane;
    float4 v = make_float4(0.f, 0.f, 0.f, 0.f);
    if (up) {
        uint4 u = *rowp;
        v.x = (u.x == SENT) ? 0.f : unflip(u.x);
        v.y = (u.y == SENT) ? 0.f : unflip(u.y);
        v.z = (u.z == SENT) ? 0.f : unflip(u.z);
        v.w = (u.w == SENT) ? 0.f : unflip(u.w);
    }
    *(float4*)rowp = v;
    if (lane == 0) ((float*)out)[(size_t)Bb * Nn * Hh + g] = up ? 1.0f : 0.0f;
}

extern "C" void kernel_launch(void* const* d_in, const int* in_sizes, int n_in,
                              void* d_out, int out_size, void* d_ws, size_t ws_size,
                              hipStream_t stream) {
    const float* h    = (const float*)d_in[0];
    const float* sl   = (const float*)d_in[1];
    const float* sc   = (const float*)d_in[2];
    const float* W    = (const float*)d_in[3];
    const float* bias = (const float*)d_in[4];

    char* ws = (char*)d_ws;
    int* mask = (int*)ws;                 ws += (size_t)Bb * Nn * sizeof(int);
    int* knn  = (int*)ws;                 ws += (size_t)Bb * Nn * MM * sizeof(int);
    float4* upc = (float4*)ws;            ws += (size_t)Bb * NUP * sizeof(float4);
    unsigned short* Wt = (unsigned short*)ws;  // 256*KP bf16
    unsigned* outu = (unsigned*)d_out;
    // Pre-feat scratch: partial KNN lists live in d_out; feat_mfma overwrites.
    uint2* part = (uint2*)d_out;

    dim3 blk(256);
    select_kernel<<<dim3(Bb), dim3(1024), 0, stream>>>(sc, sl, mask, upc);
    wt_kernel<<<dim3(Hh), blk, 0, stream>>>(W, bias, Wt);
    knn_partial<<<dim3(Nn / 256, NCH, Bb), blk, 0, stream>>>(sl, mask, upc, part);
    knn_merge<<<dim3(Nn / 256, Bb), blk, 0, stream>>>(mask, part, knn);
    feat_mfma<<<dim3(Nn / 128, 2, Bb), blk, 0, stream>>>(h, sl, sc, Wt, mask, outu);
    scatter_kernel<<<dim3(Nn / 4, Bb), blk, 0, stream>>>(mask, knn, outu);
    finalize_kernel<<<dim3(Nn / 4, Bb), blk, 0, stream>>>(mask, outu);
}

// Round 6
// 475.080 us; speedup vs baseline: 3.1188x; 1.0721x over previous
//
#include <hip/hip_runtime.h>

#define Bb 8
#define Nn 8192
#define Hh 256
#define NUP 2048
#define MM 5
#define NCH 4
#define CHSZ (NUP / NCH)   // 512 candidates per chunk
#define KP 288             // padded K for the feat GEMM (256 h + sl,score,1,pad)
#define LDA 36             // LDS row stride (bf16) for A/B tiles

typedef short v8s __attribute__((ext_vector_type(8)));
typedef float v4f __attribute__((ext_vector_type(4)));

#define SENT 0x007FFFFFu   // flipf(-inf)

__device__ __forceinline__ unsigned flipf(float f) {
    unsigned u = __float_as_uint(f);
    return (u & 0x80000000u) ? ~u : (u | 0x80000000u);
}
__device__ __forceinline__ float unflip(unsigned u) {
    unsigned bits = (u & 0x80000000u) ? (u & 0x7FFFFFFFu) : ~u;
    return __uint_as_float(bits);
}
// fp32 -> bf16 round-to-nearest-even
__device__ __forceinline__ unsigned short bfc(float f) {
    unsigned u = __float_as_uint(f);
    return (unsigned short)((u + 0x7FFFu + ((u >> 16) & 1u)) >> 16);
}

// Find the bin (descending order) where the kth-largest element lands.
template <int NB>
__device__ void find_kth_bin(const int* hist, int kth, int tid,
                             int* wsumA, int* res, int* out_bin, int* out_cntgt) {
    constexpr int PER = NB / 1024;
    int ln = tid & 63, wv = tid >> 6;
    int b0 = NB - 1 - PER * tid;
    int c0 = hist[b0];
    int c1 = (PER == 2) ? hist[b0 - 1] : 0;
    int tot = c0 + c1;
    int x = tot;
    #pragma unroll
    for (int off = 1; off < 64; off <<= 1) {
        int y = __shfl_up(x, off);
        if (ln >= off) x += y;
    }
    if (ln == 63) wsumA[wv] = x;
    __syncthreads();
    int wbase = 0;
    for (int w = 0; w < wv; w++) wbase += wsumA[w];
    int excl = wbase + x - tot;
    if (excl < kth && excl + c0 >= kth) { res[0] = b0; res[1] = excl; }
    else if (PER == 2 && excl + c0 < kth && excl + c0 + c1 >= kth) { res[0] = b0 - 1; res[1] = excl + c0; }
    __syncthreads();
    *out_bin = res[0];
    *out_cntgt = res[1];
}

// Kernel A: exact top-NUP selection via 3-level radix select, fused compaction.
__global__ __launch_bounds__(1024) void select_kernel(
        const float* __restrict__ scores, const float* __restrict__ sl,
        int* __restrict__ mask, float4* __restrict__ upc) {
    int b = blockIdx.x;
    int tid = threadIdx.x;
    int ln = tid & 63, wv = tid >> 6;
    __shared__ int hist[2048];
    __shared__ int wsumA[16], wsumB[16];
    __shared__ int res[2];
    __shared__ int sbase[2];
    const float* s = scores + (size_t)b * Nn;

    hist[tid] = 0; hist[tid + 1024] = 0;
    __syncthreads();
    for (int t = tid; t < Nn; t += 1024)
        atomicAdd(&hist[__float_as_uint(s[t]) >> 21], 1);
    __syncthreads();
    int B1, gt1;
    find_kth_bin<2048>(hist, NUP, tid, wsumA, res, &B1, &gt1);
    int slots1 = NUP - gt1;

    hist[tid] = 0; hist[tid + 1024] = 0;
    __syncthreads();
    for (int t = tid; t < Nn; t += 1024) {
        unsigned u = __float_as_uint(s[t]);
        if ((int)(u >> 21) == B1) atomicAdd(&hist[(u >> 10) & 0x7FF], 1);
    }
    __syncthreads();
    int B2, gt2;
    find_kth_bin<2048>(hist, slots1, tid, wsumA, res, &B2, &gt2);
    int slots2 = slots1 - gt2;
    unsigned hi22 = ((unsigned)B1 << 11) | (unsigned)B2;

    hist[tid] = 0; hist[tid + 1024] = 0;
    __syncthreads();
    for (int t = tid; t < Nn; t += 1024) {
        unsigned u = __float_as_uint(s[t]);
        if ((u >> 10) == hi22) atomicAdd(&hist[u & 0x3FF], 1);
    }
    __syncthreads();
    int B3, gt3;
    find_kth_bin<1024>(hist, slots2, tid, wsumA, res, &B3, &gt3);
    int slots_eq = slots2 - gt3;
    unsigned T = (hi22 << 10) | (unsigned)B3;

    if (tid == 0) { sbase[0] = 0; sbase[1] = 0; }
    __syncthreads();
    for (int t0 = 0; t0 < Nn; t0 += 1024) {
        int node = t0 + tid;
        int g = b * Nn + node;
        unsigned u = __float_as_uint(s[node]);
        bool eq = (u == T);
        unsigned long long bal = __ballot(eq);
        unsigned long long lmask = (1ull << ln) - 1ull;
        int pre = __popcll(bal & lmask);
        if (ln == 0) wsumA[wv] = __popcll(bal);
        __syncthreads();
        int eqbase = sbase[0];
        for (int w = 0; w < wv; w++) eqbase += wsumA[w];
        bool up = (u > T) || (eq && (eqbase + pre) < slots_eq);
        unsigned long long bal2 = __ballot(up);
        int pre2 = __popcll(bal2 & lmask);
        if (ln == 0) wsumB[wv] = __popcll(bal2);
        __syncthreads();
        int upbase = sbase[1];
        for (int w = 0; w < wv; w++) upbase += wsumB[w];
        if (up) {
            float4 c;
            c.x = sl[(size_t)g * 3 + 0];
            c.y = sl[(size_t)g * 3 + 1];
            c.z = sl[(size_t)g * 3 + 2];
            c.w = __int_as_float(node);
            upc[b * NUP + upbase + pre2] = c;
        }
        mask[g] = up ? 1 : 0;
        __syncthreads();
        if (tid == 0) {
            int se = 0, su = 0;
            for (int w = 0; w < 16; w++) { se += wsumA[w]; su += wsumB[w]; }
            sbase[0] += se; sbase[1] += su;
        }
        __syncthreads();
    }
}

// Kernel W: Wt[n][k] = bf16 of W-ext^T.
__global__ void wt_kernel(const float* __restrict__ W, const float* __restrict__ bias,
                          unsigned short* __restrict__ Wt) {
    int n = blockIdx.x;
    int k = threadIdx.x;
    Wt[n * KP + k] = bfc(W[(size_t)k * Hh + n]);
    if (k < KP - 256) {
        int kk = 256 + k;
        unsigned short v = 0;
        if (kk < 260)       v = bfc(W[(size_t)kk * Hh + n]);
        else if (kk == 260) v = bfc(bias[n]);
        Wt[n * KP + kk] = v;
    }
}

// Kernel B: feat GEMM via bf16 MFMA. C[128m x 128n] per block, 4 waves of 64x64.
__global__ void feat_mfma(const float* __restrict__ h, const float* __restrict__ sl,
                          const float* __restrict__ sc, const unsigned short* __restrict__ Wt,
                          const int* __restrict__ mask, unsigned* __restrict__ out) {
    int b = blockIdx.z;
    int m0 = blockIdx.x * 128;
    int n0 = blockIdx.y * 128;
    int tid = threadIdx.x;
    __shared__ unsigned short Al[128 * LDA];
    __shared__ unsigned short Bl[128 * LDA];
    int wid = tid >> 6, lane = tid & 63;
    int wm = (wid & 1) * 64, wn = (wid >> 1) * 64;
    int lm = lane & 15, quad = lane >> 4;
    v4f acc[4][4];
    #pragma unroll
    for (int i = 0; i < 4; i++)
        #pragma unroll
        for (int j = 0; j < 4; j++)
            acc[i][j] = (v4f){0.f, 0.f, 0.f, 0.f};
    const float* Ab = h + ((size_t)b * Nn + m0) * Hh;
    for (int t = 0; t < 9; t++) {
        int k0 = t * 32;
        __syncthreads();
        if (t < 8) {
            #pragma unroll
            for (int q = 0; q < 4; q++) {
                int e = q * 256 + tid;
                int row = e >> 3, kq = e & 7;
                float4 v = *(const float4*)(Ab + (size_t)row * Hh + k0 + kq * 4);
                ushort4 o = make_ushort4(bfc(v.x), bfc(v.y), bfc(v.z), bfc(v.w));
                *(ushort4*)(Al + row * LDA + kq * 4) = o;
            }
        } else if (tid < 128) {
            int row = tid;
            int g = b * Nn + m0 + row;
            unsigned short r[32];
            #pragma unroll
            for (int k = 0; k < 32; k++) r[k] = 0;
            r[0] = bfc(sl[(size_t)g * 3 + 0]);
            r[1] = bfc(sl[(size_t)g * 3 + 1]);
            r[2] = bfc(sl[(size_t)g * 3 + 2]);
            r[3] = bfc(sc[g]);
            r[4] = 0x3F80;  // 1.0 (bias column)
            #pragma unroll
            for (int q = 0; q < 8; q++)
                *(ushort4*)(Al + row * LDA + q * 4) =
                    make_ushort4(r[q * 4], r[q * 4 + 1], r[q * 4 + 2], r[q * 4 + 3]);
        }
        #pragma unroll
        for (int q = 0; q < 4; q++) {
            int e = q * 256 + tid;
            int n = e >> 3, kq = e & 7;
            ushort4 v = *(const ushort4*)(Wt + (size_t)(n0 + n) * KP + k0 + kq * 4);
            *(ushort4*)(Bl + n * LDA + kq * 4) = v;
        }
        __syncthreads();
        v8s af[4], bfr[4];
        #pragma unroll
        for (int i = 0; i < 4; i++)
            af[i] = *(const v8s*)(Al + (wm + i * 16 + lm) * LDA + quad * 8);
        #pragma unroll
        for (int j = 0; j < 4; j++)
            bfr[j] = *(const v8s*)(Bl + (wn + j * 16 + lm) * LDA + quad * 8);
        #pragma unroll
        for (int i = 0; i < 4; i++)
            #pragma unroll
            for (int j = 0; j < 4; j++)
                acc[i][j] = __builtin_amdgcn_mfma_f32_16x16x32_bf16(af[i], bfr[j], acc[i][j], 0, 0, 0);
    }
    #pragma unroll
    for (int i = 0; i < 4; i++) {
        #pragma unroll
        for (int r = 0; r < 4; r++) {
            int row = m0 + wm + i * 16 + quad * 4 + r;
            int g = b * Nn + row;
            bool up = mask[g] != 0;
            size_t base = (size_t)g * Hh + n0 + wn + lm;
            #pragma unroll
            for (int j = 0; j < 4; j++)
                out[base + j * 16] = up ? SENT : __float_as_uint(acc[i][j][r]);
        }
    }
}

// Branchless sorted-insert of (dd, ii) into list L (ascending d).
#define INS(L, dd, ii)                                                        \
    {                                                                         \
        float cd = (dd); int cj = (ii);                                       \
        _Pragma("unroll")                                                     \
        for (int p = 0; p < MM; p++) {                                        \
            bool c = cd < bd[L][p];                                           \
            float nd = c ? cd : bd[L][p]; float od = c ? bd[L][p] : cd;       \
            int   nj = c ? cj : bj[L][p]; int   oj = c ? bj[L][p] : cj;       \
            bd[L][p] = nd; bj[L][p] = nj; cd = od; cj = oj;                   \
        }                                                                     \
    }

// Kernel C1: per-chunk 5-NN, 4 independent lists per thread (breaks the serial
// insert chain -> 4x ILP), branchless inserts, 4 batched LDS reads per iter.
__global__ void knn_partial(const float* __restrict__ sl, const int* __restrict__ mask,
                            const float4* __restrict__ upc, uint2* __restrict__ part) {
    int b = blockIdx.z;
    int ch = blockIdx.y;
    int tid = threadIdx.x;
    int i = blockIdx.x * 256 + tid;
    int g = b * Nn + i;
    __shared__ float4 cand[CHSZ];
    cand[tid]       = upc[b * NUP + ch * CHSZ + tid];
    cand[256 + tid] = upc[b * NUP + ch * CHSZ + 256 + tid];
    __syncthreads();
    if (mask[g]) return;
    float xi = sl[(size_t)g * 3 + 0];
    float yi = sl[(size_t)g * 3 + 1];
    float zi = sl[(size_t)g * 3 + 2];
    float bd[4][MM];
    int bj[4][MM];
    #pragma unroll
    for (int l = 0; l < 4; l++)
        #pragma unroll
        for (int m = 0; m < MM; m++) { bd[l][m] = 3.4e38f; bj[l][m] = 0x7FFFFFFF; }
    for (int jj = 0; jj < CHSZ; jj += 4) {
        float4 c0 = cand[jj], c1 = cand[jj + 1], c2 = cand[jj + 2], c3 = cand[jj + 3];
        float dx, dy, dz;
        dx = c0.x - xi; dy = c0.y - yi; dz = c0.z - zi;
        float d0 = fmaf(dx, dx, fmaf(dy, dy, dz * dz));
        dx = c1.x - xi; dy = c1.y - yi; dz = c1.z - zi;
        float d1 = fmaf(dx, dx, fmaf(dy, dy, dz * dz));
        dx = c2.x - xi; dy = c2.y - yi; dz = c2.z - zi;
        float d2 = fmaf(dx, dx, fmaf(dy, dy, dz * dz));
        dx = c3.x - xi; dy = c3.y - yi; dz = c3.z - zi;
        float d3 = fmaf(dx, dx, fmaf(dy, dy, dz * dz));
        INS(0, d0, __float_as_int(c0.w));
        INS(1, d1, __float_as_int(c1.w));
        INS(2, d2, __float_as_int(c2.w));
        INS(3, d3, __float_as_int(c3.w));
    }
    // Lex merge of the 4 lists' 20 entries -> chunk top-5.
    float fd[MM];
    int fj[MM];
    #pragma unroll
    for (int m = 0; m < MM; m++) { fd[m] = 3.4e38f; fj[m] = 0x7FFFFFFF; }
    #pragma unroll
    for (int l = 0; l < 4; l++) {
        #pragma unroll
        for (int m = 0; m < MM; m++) {
            float cd = bd[l][m]; int cj = bj[l][m];
            #pragma unroll
            for (int p = 0; p < MM; p++) {
                bool c = cd < fd[p] || (cd == fd[p] && cj < fj[p]);
                float nd = c ? cd : fd[p]; float od = c ? fd[p] : cd;
                int   nj = c ? cj : fj[p]; int   oj = c ? fj[p] : cj;
                fd[p] = nd; fj[p] = nj; cd = od; cj = oj;
            }
        }
    }
    #pragma unroll
    for (int m = 0; m < MM; m++) {
        uint2 e; e.x = __float_as_uint(fd[m]); e.y = (unsigned)fj[m];
        part[((size_t)g * NCH + ch) * MM + m] = e;
    }
}

// Kernel C2: lexicographic (d2, idx) merge of NCH partial lists -> final 5-NN.
__global__ void knn_merge(const int* __restrict__ mask, const uint2* __restrict__ part,
                          int* __restrict__ knn) {
    int b = blockIdx.y;
    int i = blockIdx.x * 256 + threadIdx.x;
    int g = b * Nn + i;
    if (mask[g]) return;
    float bd[MM];
    int bj[MM];
    #pragma unroll
    for (int m = 0; m < MM; m++) { bd[m] = 3.4e38f; bj[m] = 0x7FFFFFFF; }
    #pragma unroll
    for (int ch = 0; ch < NCH; ch++) {
        #pragma unroll
        for (int m = 0; m < MM; m++) {
            uint2 e = part[((size_t)g * NCH + ch) * MM + m];
            float cd = __uint_as_float(e.x);
            int cj = (int)e.y;
            #pragma unroll
            for (int p = 0; p < MM; p++) {
                if (cd < bd[p] || (cd == bd[p] && cj < bj[p])) {
                    float td = bd[p]; int tj = bj[p];
                    bd[p] = cd; bj[p] = cj;
                    cd = td; cj = tj;
                }
            }
        }
    }
    #pragma unroll
    for (int m = 0; m < MM; m++) knn[g * MM + m] = bj[m];
}

// Kernel D: scatter-max. Wave-per-down-node (4 nodes per 256-thread block).
__global__ void scatter_kernel(const int* __restrict__ mask, const int* __restrict__ knn,
                               unsigned* __restrict__ out) {
    int b = blockIdx.y;
    int node = blockIdx.x * 4 + (threadIdx.x >> 6);
    int g = b * Nn + node;
    if (mask[g]) return;
    int lane = threadIdx.x & 63;
    unsigned e[4];
    #pragma unroll
    for (int q = 0; q < 4; q++) {
        float f = __uint_as_float(out[(size_t)g * Hh + lane + 64 * q]);
        e[q] = flipf(f);
    }
    int nb[MM];
    #pragma unroll
    for (int m = 0; m < MM; m++) nb[m] = knn[g * MM + m];
    #pragma unroll
    for (int m = 0; m < MM; m++) {
        size_t base = ((size_t)(b * Nn + nb[m])) * Hh;
        #pragma unroll
        for (int q = 0; q < 4; q++) atomicMax(&out[base + lane + 64 * q], e[q]);
    }
}

// Kernel E: decode up rows (sentinel -> 0), zero down rows, write mask tail.
__global__ void finalize_kernel(const int* __restrict__ mask, unsigned* __restrict__ out) {
    int b = blockIdx.y;
    int node = blockIdx.x * 4 + (threadIdx.x >> 6);
    int g = b * Nn + node;
    int lane = threadIdx.x & 63;
    bool up = mask[g] != 0;
    uint4* rowp = (uint4*)(out + (size_t)g * Hh) + lane;
    float4 v = make_float4(0.f, 0.f, 0.f, 0.f);
    if (up) {
        uint4 u = *rowp;
        v.x = (u.x == SENT) ? 0.f : unflip(u.x);
        v.y = (u.y == SENT) ? 0.f : unflip(u.y);
        v.z = (u.z == SENT) ? 0.f : unflip(u.z);
        v.w = (u.w == SENT) ? 0.f : unflip(u.w);
    }
    *(float4*)rowp = v;
    if (lane == 0) ((float*)out)[(size_t)Bb * Nn * Hh + g] = up ? 1.0f : 0.0f;
}

extern "C" void kernel_launch(void* const* d_in, const int* in_sizes, int n_in,
                              void* d_out, int out_size, void* d_ws, size_t ws_size,
                              hipStream_t stream) {
    const float* h    = (const float*)d_in[0];
    const float* sl   = (const float*)d_in[1];
    const float* sc   = (const float*)d_in[2];
    const float* W    = (const float*)d_in[3];
    const float* bias = (const float*)d_in[4];

    char* ws = (char*)d_ws;
    int* mask = (int*)ws;                 ws += (size_t)Bb * Nn * sizeof(int);
    int* knn  = (int*)ws;                 ws += (size_t)Bb * Nn * MM * sizeof(int);
    float4* upc = (float4*)ws;            ws += (size_t)Bb * NUP * sizeof(float4);
    unsigned short* Wt = (unsigned short*)ws;  // 256*KP bf16
    unsigned* outu = (unsigned*)d_out;
    // Pre-feat scratch: partial KNN lists live in d_out; feat_mfma overwrites.
    uint2* part = (uint2*)d_out;

    dim3 blk(256);
    select_kernel<<<dim3(Bb), dim3(1024), 0, stream>>>(sc, sl, mask, upc);
    wt_kernel<<<dim3(Hh), blk, 0, stream>>>(W, bias, Wt);
    knn_partial<<<dim3(Nn / 256, NCH, Bb), blk, 0, stream>>>(sl, mask, upc, part);
    knn_merge<<<dim3(Nn / 256, Bb), blk, 0, stream>>>(mask, part, knn);
    feat_mfma<<<dim3(Nn / 128, 2, Bb), blk, 0, stream>>>(h, sl, sc, Wt, mask, outu);
    scatter_kernel<<<dim3(Nn / 4, Bb), blk, 0, stream>>>(mask, knn, outu);
    finalize_kernel<<<dim3(Nn / 4, Bb), blk, 0, stream>>>(mask, outu);
}

// Round 7
// 371.908 us; speedup vs baseline: 3.9840x; 1.2774x over previous
//
#include <hip/hip_runtime.h>

#define Bb 8
#define Nn 8192
#define Hh 256
#define NUP 2048
#define NDOWN (Nn - NUP)
#define EPB (NDOWN * MM)   // edges per batch = 30720
#define MM 5
#define NCH 4
#define CHSZ (NUP / NCH)   // 512 candidates per chunk
#define KP 288             // padded K for the feat GEMM (256 h + sl,score,1,pad)
#define LDA 36             // LDS row stride (bf16) for A/B tiles

typedef short v8s __attribute__((ext_vector_type(8)));
typedef float v4f __attribute__((ext_vector_type(4)));

// fp32 -> bf16 round-to-nearest-even
__device__ __forceinline__ unsigned short bfc(float f) {
    unsigned u = __float_as_uint(f);
    return (unsigned short)((u + 0x7FFFu + ((u >> 16) & 1u)) >> 16);
}

// Find the bin (descending order) where the kth-largest element lands.
template <int NB>
__device__ void find_kth_bin(const int* hist, int kth, int tid,
                             int* wsumA, int* res, int* out_bin, int* out_cntgt) {
    constexpr int PER = NB / 1024;
    int ln = tid & 63, wv = tid >> 6;
    int b0 = NB - 1 - PER * tid;
    int c0 = hist[b0];
    int c1 = (PER == 2) ? hist[b0 - 1] : 0;
    int tot = c0 + c1;
    int x = tot;
    #pragma unroll
    for (int off = 1; off < 64; off <<= 1) {
        int y = __shfl_up(x, off);
        if (ln >= off) x += y;
    }
    if (ln == 63) wsumA[wv] = x;
    __syncthreads();
    int wbase = 0;
    for (int w = 0; w < wv; w++) wbase += wsumA[w];
    int excl = wbase + x - tot;
    if (excl < kth && excl + c0 >= kth) { res[0] = b0; res[1] = excl; }
    else if (PER == 2 && excl + c0 < kth && excl + c0 + c1 >= kth) { res[0] = b0 - 1; res[1] = excl + c0; }
    __syncthreads();
    *out_bin = res[0];
    *out_cntgt = res[1];
}

// Kernel A: exact top-NUP selection via 3-level radix select, fused compaction
// + up_local inverse map + deg zeroing (for the later CSR build).
__global__ __launch_bounds__(1024) void select_kernel(
        const float* __restrict__ scores, const float* __restrict__ sl,
        int* __restrict__ mask, float4* __restrict__ upc,
        int* __restrict__ up_local, int* __restrict__ deg) {
    int b = blockIdx.x;
    int tid = threadIdx.x;
    int ln = tid & 63, wv = tid >> 6;
    __shared__ int hist[2048];
    __shared__ int wsumA[16], wsumB[16];
    __shared__ int res[2];
    __shared__ int sbase[2];
    const float* s = scores + (size_t)b * Nn;

    deg[b * NUP + tid] = 0;
    deg[b * NUP + 1024 + tid] = 0;

    hist[tid] = 0; hist[tid + 1024] = 0;
    __syncthreads();
    for (int t = tid; t < Nn; t += 1024)
        atomicAdd(&hist[__float_as_uint(s[t]) >> 21], 1);
    __syncthreads();
    int B1, gt1;
    find_kth_bin<2048>(hist, NUP, tid, wsumA, res, &B1, &gt1);
    int slots1 = NUP - gt1;

    hist[tid] = 0; hist[tid + 1024] = 0;
    __syncthreads();
    for (int t = tid; t < Nn; t += 1024) {
        unsigned u = __float_as_uint(s[t]);
        if ((int)(u >> 21) == B1) atomicAdd(&hist[(u >> 10) & 0x7FF], 1);
    }
    __syncthreads();
    int B2, gt2;
    find_kth_bin<2048>(hist, slots1, tid, wsumA, res, &B2, &gt2);
    int slots2 = slots1 - gt2;
    unsigned hi22 = ((unsigned)B1 << 11) | (unsigned)B2;

    hist[tid] = 0; hist[tid + 1024] = 0;
    __syncthreads();
    for (int t = tid; t < Nn; t += 1024) {
        unsigned u = __float_as_uint(s[t]);
        if ((u >> 10) == hi22) atomicAdd(&hist[u & 0x3FF], 1);
    }
    __syncthreads();
    int B3, gt3;
    find_kth_bin<1024>(hist, slots2, tid, wsumA, res, &B3, &gt3);
    int slots_eq = slots2 - gt3;
    unsigned T = (hi22 << 10) | (unsigned)B3;

    if (tid == 0) { sbase[0] = 0; sbase[1] = 0; }
    __syncthreads();
    for (int t0 = 0; t0 < Nn; t0 += 1024) {
        int node = t0 + tid;
        int g = b * Nn + node;
        unsigned u = __float_as_uint(s[node]);
        bool eq = (u == T);
        unsigned long long bal = __ballot(eq);
        unsigned long long lmask = (1ull << ln) - 1ull;
        int pre = __popcll(bal & lmask);
        if (ln == 0) wsumA[wv] = __popcll(bal);
        __syncthreads();
        int eqbase = sbase[0];
        for (int w = 0; w < wv; w++) eqbase += wsumA[w];
        bool up = (u > T) || (eq && (eqbase + pre) < slots_eq);
        unsigned long long bal2 = __ballot(up);
        int pre2 = __popcll(bal2 & lmask);
        if (ln == 0) wsumB[wv] = __popcll(bal2);
        __syncthreads();
        int upbase = sbase[1];
        for (int w = 0; w < wv; w++) upbase += wsumB[w];
        if (up) {
            float4 c;
            c.x = sl[(size_t)g * 3 + 0];
            c.y = sl[(size_t)g * 3 + 1];
            c.z = sl[(size_t)g * 3 + 2];
            c.w = __int_as_float(node);
            upc[b * NUP + upbase + pre2] = c;
            up_local[g] = upbase + pre2;
        }
        mask[g] = up ? 1 : 0;
        __syncthreads();
        if (tid == 0) {
            int se = 0, su = 0;
            for (int w = 0; w < 16; w++) { se += wsumA[w]; su += wsumB[w]; }
            sbase[0] += se; sbase[1] += su;
        }
        __syncthreads();
    }
}

// Kernel W: Wt[n][k] = bf16 of W-ext^T.
__global__ void wt_kernel(const float* __restrict__ W, const float* __restrict__ bias,
                          unsigned short* __restrict__ Wt) {
    int n = blockIdx.x;
    int k = threadIdx.x;
    Wt[n * KP + k] = bfc(W[(size_t)k * Hh + n]);
    if (k < KP - 256) {
        int kk = 256 + k;
        unsigned short v = 0;
        if (kk < 260)       v = bfc(W[(size_t)kk * Hh + n]);
        else if (kk == 260) v = bfc(bias[n]);
        Wt[n * KP + kk] = v;
    }
}

// Kernel B: feat GEMM via bf16 MFMA. C[128m x 128n] per block, 4 waves of 64x64.
// Writes plain fp32 feat for ALL rows (up rows get overwritten by gather).
__global__ void feat_mfma(const float* __restrict__ h, const float* __restrict__ sl,
                          const float* __restrict__ sc, const unsigned short* __restrict__ Wt,
                          float* __restrict__ out) {
    int b = blockIdx.z;
    int m0 = blockIdx.x * 128;
    int n0 = blockIdx.y * 128;
    int tid = threadIdx.x;
    __shared__ unsigned short Al[128 * LDA];
    __shared__ unsigned short Bl[128 * LDA];
    int wid = tid >> 6, lane = tid & 63;
    int wm = (wid & 1) * 64, wn = (wid >> 1) * 64;
    int lm = lane & 15, quad = lane >> 4;
    v4f acc[4][4];
    #pragma unroll
    for (int i = 0; i < 4; i++)
        #pragma unroll
        for (int j = 0; j < 4; j++)
            acc[i][j] = (v4f){0.f, 0.f, 0.f, 0.f};
    const float* Ab = h + ((size_t)b * Nn + m0) * Hh;
    for (int t = 0; t < 9; t++) {
        int k0 = t * 32;
        __syncthreads();
        if (t < 8) {
            #pragma unroll
            for (int q = 0; q < 4; q++) {
                int e = q * 256 + tid;
                int row = e >> 3, kq = e & 7;
                float4 v = *(const float4*)(Ab + (size_t)row * Hh + k0 + kq * 4);
                ushort4 o = make_ushort4(bfc(v.x), bfc(v.y), bfc(v.z), bfc(v.w));
                *(ushort4*)(Al + row * LDA + kq * 4) = o;
            }
        } else if (tid < 128) {
            int row = tid;
            int g = b * Nn + m0 + row;
            unsigned short r[32];
            #pragma unroll
            for (int k = 0; k < 32; k++) r[k] = 0;
            r[0] = bfc(sl[(size_t)g * 3 + 0]);
            r[1] = bfc(sl[(size_t)g * 3 + 1]);
            r[2] = bfc(sl[(size_t)g * 3 + 2]);
            r[3] = bfc(sc[g]);
            r[4] = 0x3F80;  // 1.0 (bias column)
            #pragma unroll
            for (int q = 0; q < 8; q++)
                *(ushort4*)(Al + row * LDA + q * 4) =
                    make_ushort4(r[q * 4], r[q * 4 + 1], r[q * 4 + 2], r[q * 4 + 3]);
        }
        #pragma unroll
        for (int q = 0; q < 4; q++) {
            int e = q * 256 + tid;
            int n = e >> 3, kq = e & 7;
            ushort4 v = *(const ushort4*)(Wt + (size_t)(n0 + n) * KP + k0 + kq * 4);
            *(ushort4*)(Bl + n * LDA + kq * 4) = v;
        }
        __syncthreads();
        v8s af[4], bfr[4];
        #pragma unroll
        for (int i = 0; i < 4; i++)
            af[i] = *(const v8s*)(Al + (wm + i * 16 + lm) * LDA + quad * 8);
        #pragma unroll
        for (int j = 0; j < 4; j++)
            bfr[j] = *(const v8s*)(Bl + (wn + j * 16 + lm) * LDA + quad * 8);
        #pragma unroll
        for (int i = 0; i < 4; i++)
            #pragma unroll
            for (int j = 0; j < 4; j++)
                acc[i][j] = __builtin_amdgcn_mfma_f32_16x16x32_bf16(af[i], bfr[j], acc[i][j], 0, 0, 0);
    }
    #pragma unroll
    for (int i = 0; i < 4; i++) {
        #pragma unroll
        for (int r = 0; r < 4; r++) {
            int row = m0 + wm + i * 16 + quad * 4 + r;
            size_t base = ((size_t)b * Nn + row) * Hh + n0 + wn + lm;
            #pragma unroll
            for (int j = 0; j < 4; j++)
                out[base + j * 16] = acc[i][j][r];
        }
    }
}

// Branchless sorted-insert of (dd, ii) into list L (ascending d).
#define INS(L, dd, ii)                                                        \
    {                                                                         \
        float cd = (dd); int cj = (ii);                                       \
        _Pragma("unroll")                                                     \
        for (int p = 0; p < MM; p++) {                                        \
            bool c = cd < bd[L][p];                                           \
            float nd = c ? cd : bd[L][p]; float od = c ? bd[L][p] : cd;       \
            int   nj = c ? cj : bj[L][p]; int   oj = c ? bj[L][p] : cj;       \
            bd[L][p] = nd; bj[L][p] = nj; cd = od; cj = oj;                   \
        }                                                                     \
    }

// Kernel C1: per-chunk 5-NN, 4 independent branchless lists per thread.
__global__ void knn_partial(const float* __restrict__ sl, const int* __restrict__ mask,
                            const float4* __restrict__ upc, uint2* __restrict__ part) {
    int b = blockIdx.z;
    int ch = blockIdx.y;
    int tid = threadIdx.x;
    int i = blockIdx.x * 256 + tid;
    int g = b * Nn + i;
    __shared__ float4 cand[CHSZ];
    cand[tid]       = upc[b * NUP + ch * CHSZ + tid];
    cand[256 + tid] = upc[b * NUP + ch * CHSZ + 256 + tid];
    __syncthreads();
    if (mask[g]) return;
    float xi = sl[(size_t)g * 3 + 0];
    float yi = sl[(size_t)g * 3 + 1];
    float zi = sl[(size_t)g * 3 + 2];
    float bd[4][MM];
    int bj[4][MM];
    #pragma unroll
    for (int l = 0; l < 4; l++)
        #pragma unroll
        for (int m = 0; m < MM; m++) { bd[l][m] = 3.4e38f; bj[l][m] = 0x7FFFFFFF; }
    for (int jj = 0; jj < CHSZ; jj += 4) {
        float4 c0 = cand[jj], c1 = cand[jj + 1], c2 = cand[jj + 2], c3 = cand[jj + 3];
        float dx, dy, dz;
        dx = c0.x - xi; dy = c0.y - yi; dz = c0.z - zi;
        float d0 = fmaf(dx, dx, fmaf(dy, dy, dz * dz));
        dx = c1.x - xi; dy = c1.y - yi; dz = c1.z - zi;
        float d1 = fmaf(dx, dx, fmaf(dy, dy, dz * dz));
        dx = c2.x - xi; dy = c2.y - yi; dz = c2.z - zi;
        float d2 = fmaf(dx, dx, fmaf(dy, dy, dz * dz));
        dx = c3.x - xi; dy = c3.y - yi; dz = c3.z - zi;
        float d3 = fmaf(dx, dx, fmaf(dy, dy, dz * dz));
        INS(0, d0, __float_as_int(c0.w));
        INS(1, d1, __float_as_int(c1.w));
        INS(2, d2, __float_as_int(c2.w));
        INS(3, d3, __float_as_int(c3.w));
    }
    float fd[MM];
    int fj[MM];
    #pragma unroll
    for (int m = 0; m < MM; m++) { fd[m] = 3.4e38f; fj[m] = 0x7FFFFFFF; }
    #pragma unroll
    for (int l = 0; l < 4; l++) {
        #pragma unroll
        for (int m = 0; m < MM; m++) {
            float cd = bd[l][m]; int cj = bj[l][m];
            #pragma unroll
            for (int p = 0; p < MM; p++) {
                bool c = cd < fd[p] || (cd == fd[p] && cj < fj[p]);
                float nd = c ? cd : fd[p]; float od = c ? fd[p] : cd;
                int   nj = c ? cj : fj[p]; int   oj = c ? fj[p] : cj;
                fd[p] = nd; fj[p] = nj; cd = od; cj = oj;
            }
        }
    }
    #pragma unroll
    for (int m = 0; m < MM; m++) {
        uint2 e; e.x = __float_as_uint(fd[m]); e.y = (unsigned)fj[m];
        part[((size_t)g * NCH + ch) * MM + m] = e;
    }
}

// Kernel C2: lexicographic (d2, idx) merge of NCH partial lists -> final 5-NN.
__global__ void knn_merge(const int* __restrict__ mask, const uint2* __restrict__ part,
                          int* __restrict__ knn) {
    int b = blockIdx.y;
    int i = blockIdx.x * 256 + threadIdx.x;
    int g = b * Nn + i;
    if (mask[g]) return;
    float bd[MM];
    int bj[MM];
    #pragma unroll
    for (int m = 0; m < MM; m++) { bd[m] = 3.4e38f; bj[m] = 0x7FFFFFFF; }
    #pragma unroll
    for (int ch = 0; ch < NCH; ch++) {
        #pragma unroll
        for (int m = 0; m < MM; m++) {
            uint2 e = part[((size_t)g * NCH + ch) * MM + m];
            float cd = __uint_as_float(e.x);
            int cj = (int)e.y;
            #pragma unroll
            for (int p = 0; p < MM; p++) {
                if (cd < bd[p] || (cd == bd[p] && cj < bj[p])) {
                    float td = bd[p]; int tj = bj[p];
                    bd[p] = cd; bj[p] = cj;
                    cd = td; cj = tj;
                }
            }
        }
    }
    #pragma unroll
    for (int m = 0; m < MM; m++) knn[g * MM + m] = bj[m];
}

// CSR build: count in-degree of each up node.
__global__ void csr_count(const int* __restrict__ mask, const int* __restrict__ knn,
                          const int* __restrict__ up_local, int* __restrict__ deg) {
    int b = blockIdx.y;
    int i = blockIdx.x * 256 + threadIdx.x;
    int g = b * Nn + i;
    if (mask[g]) return;
    #pragma unroll
    for (int m = 0; m < MM; m++) {
        int un = knn[g * MM + m];                  // batch-local up node id
        atomicAdd(&deg[b * NUP + up_local[b * Nn + un]], 1);
    }
}

// CSR build: per-batch exclusive scan of deg -> rowptr (+ cursor copy).
__global__ __launch_bounds__(1024) void csr_scan(const int* __restrict__ deg,
                                                 int* __restrict__ rowptr,
                                                 int* __restrict__ cursor) {
    int b = blockIdx.x;
    int tid = threadIdx.x;
    int ln = tid & 63, wv = tid >> 6;
    __shared__ int wsum[16];
    int d0 = deg[b * NUP + 2 * tid], d1 = deg[b * NUP + 2 * tid + 1];
    int s = d0 + d1;
    int x = s;
    #pragma unroll
    for (int off = 1; off < 64; off <<= 1) {
        int y = __shfl_up(x, off);
        if (ln >= off) x += y;
    }
    if (ln == 63) wsum[wv] = x;
    __syncthreads();
    int base = 0;
    for (int w = 0; w < wv; w++) base += wsum[w];
    int excl = base + x - s;
    rowptr[b * (NUP + 1) + 2 * tid] = excl;
    rowptr[b * (NUP + 1) + 2 * tid + 1] = excl + d0;
    cursor[b * NUP + 2 * tid] = excl;
    cursor[b * NUP + 2 * tid + 1] = excl + d0;
    if (tid == 1023) rowptr[b * (NUP + 1) + NUP] = excl + s;
}

// CSR build: fill edge array (src = batch-local down node id).
__global__ void csr_fill(const int* __restrict__ mask, const int* __restrict__ knn,
                         const int* __restrict__ up_local, int* __restrict__ cursor,
                         int* __restrict__ edges) {
    int b = blockIdx.y;
    int i = blockIdx.x * 256 + threadIdx.x;
    int g = b * Nn + i;
    if (mask[g]) return;
    #pragma unroll
    for (int m = 0; m < MM; m++) {
        int un = knn[g * MM + m];
        int slot = atomicAdd(&cursor[b * NUP + up_local[b * Nn + un]], 1);
        edges[b * EPB + slot] = i;
    }
}

// Kernel D: gather-max. One wave per up node; lanes own 4 cols (float4).
// Reads source down rows (cache-resident), writes each output element once.
__global__ void gather_kernel(const float4* __restrict__ upc, const int* __restrict__ rowptr,
                              const int* __restrict__ edges, float* __restrict__ out) {
    int b = blockIdx.y;
    int u = blockIdx.x * 4 + (threadIdx.x >> 6);
    int lane = threadIdx.x & 63;
    int node = __float_as_int(upc[b * NUP + u].w);   // batch-local up node id
    int start = rowptr[b * (NUP + 1) + u];
    int end   = rowptr[b * (NUP + 1) + u + 1];
    const int* eb = edges + b * EPB;
    size_t rowbase = (size_t)b * Nn * Hh + (size_t)(lane << 2);
    float4 a0 = make_float4(-3.4e38f, -3.4e38f, -3.4e38f, -3.4e38f);
    float4 a1 = a0;
    int e = start;
    for (; e + 2 <= end; e += 2) {
        int s0 = eb[e], s1 = eb[e + 1];
        float4 v0 = *(const float4*)(out + rowbase + (size_t)s0 * Hh);
        float4 v1 = *(const float4*)(out + rowbase + (size_t)s1 * Hh);
        a0.x = fmaxf(a0.x, v0.x); a0.y = fmaxf(a0.y, v0.y);
        a0.z = fmaxf(a0.z, v0.z); a0.w = fmaxf(a0.w, v0.w);
        a1.x = fmaxf(a1.x, v1.x); a1.y = fmaxf(a1.y, v1.y);
        a1.z = fmaxf(a1.z, v1.z); a1.w = fmaxf(a1.w, v1.w);
    }
    if (e < end) {
        int s0 = eb[e];
        float4 v0 = *(const float4*)(out + rowbase + (size_t)s0 * Hh);
        a0.x = fmaxf(a0.x, v0.x); a0.y = fmaxf(a0.y, v0.y);
        a0.z = fmaxf(a0.z, v0.z); a0.w = fmaxf(a0.w, v0.w);
    }
    float4 r;
    r.x = fmaxf(a0.x, a1.x); r.y = fmaxf(a0.y, a1.y);
    r.z = fmaxf(a0.z, a1.z); r.w = fmaxf(a0.w, a1.w);
    if (start == end) r = make_float4(0.f, 0.f, 0.f, 0.f);
    *(float4*)(out + rowbase + (size_t)node * Hh) = r;
}

// Kernel E: zero down rows, write mask tail.
__global__ void finalize_kernel(const int* __restrict__ mask, float* __restrict__ out) {
    int b = blockIdx.y;
    int node = blockIdx.x * 4 + (threadIdx.x >> 6);
    int g = b * Nn + node;
    int lane = threadIdx.x & 63;
    bool up = mask[g] != 0;
    if (!up)
        *(float4*)(out + (size_t)g * Hh + (lane << 2)) = make_float4(0.f, 0.f, 0.f, 0.f);
    if (lane == 0) out[(size_t)Bb * Nn * Hh + g] = up ? 1.0f : 0.0f;
}

extern "C" void kernel_launch(void* const* d_in, const int* in_sizes, int n_in,
                              void* d_out, int out_size, void* d_ws, size_t ws_size,
                              hipStream_t stream) {
    const float* h    = (const float*)d_in[0];
    const float* sl   = (const float*)d_in[1];
    const float* sc   = (const float*)d_in[2];
    const float* W    = (const float*)d_in[3];
    const float* bias = (const float*)d_in[4];

    char* ws = (char*)d_ws;
    int* mask = (int*)ws;                 ws += (size_t)Bb * Nn * sizeof(int);
    int* knn  = (int*)ws;                 ws += (size_t)Bb * Nn * MM * sizeof(int);
    float4* upc = (float4*)ws;            ws += (size_t)Bb * NUP * sizeof(float4);
    unsigned short* Wt = (unsigned short*)ws; ws += (size_t)Hh * KP * sizeof(unsigned short);
    int* up_local = (int*)ws;             ws += (size_t)Bb * Nn * sizeof(int);
    int* deg = (int*)ws;                  ws += (size_t)Bb * NUP * sizeof(int);
    int* cursor = (int*)ws;               ws += (size_t)Bb * NUP * sizeof(int);
    int* rowptr = (int*)ws;               ws += (size_t)Bb * (NUP + 1) * sizeof(int);
    int* edges = (int*)ws;                // B*EPB ints
    float* outf = (float*)d_out;
    // Pre-feat scratch: partial KNN lists live in d_out; feat_mfma overwrites.
    uint2* part = (uint2*)d_out;

    dim3 blk(256);
    select_kernel<<<dim3(Bb), dim3(1024), 0, stream>>>(sc, sl, mask, upc, up_local, deg);
    wt_kernel<<<dim3(Hh), blk, 0, stream>>>(W, bias, Wt);
    knn_partial<<<dim3(Nn / 256, NCH, Bb), blk, 0, stream>>>(sl, mask, upc, part);
    knn_merge<<<dim3(Nn / 256, Bb), blk, 0, stream>>>(mask, part, knn);
    csr_count<<<dim3(Nn / 256, Bb), blk, 0, stream>>>(mask, knn, up_local, deg);
    csr_scan<<<dim3(Bb), dim3(1024), 0, stream>>>(deg, rowptr, cursor);
    csr_fill<<<dim3(Nn / 256, Bb), blk, 0, stream>>>(mask, knn, up_local, cursor, edges);
    feat_mfma<<<dim3(Nn / 128, 2, Bb), blk, 0, stream>>>(h, sl, sc, Wt, outf);
    gather_kernel<<<dim3(NUP / 4, Bb), blk, 0, stream>>>(upc, rowptr, edges, outf);
    finalize_kernel<<<dim3(Nn / 4, Bb), blk, 0, stream>>>(mask, outf);
}